// Round 1
// baseline (1636.921 us; speedup 1.0000x reference)
//
#include <hip/hip_runtime.h>
#include <math.h>

// Problem constants
#define BATCH 8
#define SEQ 512
#define HID 768
#define NHEAD 12
#define KVHEAD 4
#define HDIM 64
#define NEXP 8
#define TOPK 2
#define IEXP 1536
#define NTOK (BATCH * SEQ)     // 4096
#define NSLOT (NTOK * TOPK)    // 8192
#define REP (NHEAD / KVHEAD)   // 3

// ---------------------------------------------------------------------------
// RMSNorm: one block per token, 256 threads, 3 elems/thread
// ---------------------------------------------------------------------------
__global__ __launch_bounds__(256)
void rmsnorm_kernel(const float* __restrict__ X, const float* __restrict__ W,
                    float* __restrict__ Y) {
    const int t = blockIdx.x;
    const int tid = threadIdx.x;
    const float* x = X + (size_t)t * HID;
    float* y = Y + (size_t)t * HID;
    float x0 = x[tid], x1 = x[tid + 256], x2 = x[tid + 512];
    float ss = x0 * x0 + x1 * x1 + x2 * x2;
    for (int m = 1; m < 64; m <<= 1) ss += __shfl_xor(ss, m);
    __shared__ float red[4];
    if ((tid & 63) == 0) red[tid >> 6] = ss;
    __syncthreads();
    float tot = red[0] + red[1] + red[2] + red[3];
    float inv = rsqrtf(tot * (1.0f / HID) + 1e-6f);
    y[tid]       = x0 * inv * W[tid];
    y[tid + 256] = x1 * inv * W[tid + 256];
    y[tid + 512] = x2 * inv * W[tid + 512];
}

// ---------------------------------------------------------------------------
// Generic NT GEMM: C[M,N] = A[M,K] @ W[N,K]^T (+bias) (+resid). 64x64 tile.
// M,N multiples of 64; K multiple of 16.
// ---------------------------------------------------------------------------
__global__ __launch_bounds__(256)
void gemm_nt(const float* __restrict__ A, const float* __restrict__ W,
             const float* __restrict__ bias, const float* __restrict__ resid,
             float* __restrict__ C, int M, int N, int K) {
    __shared__ float As[16][68];
    __shared__ float Ws[16][68];
    const int tid = threadIdx.x;
    const int tx = tid & 15, ty = tid >> 4;
    const int m0 = blockIdx.y << 6, n0 = blockIdx.x << 6;
    const int lr = tid >> 2;
    const int lk = (tid & 3) << 2;
    const float* Ap = A + (size_t)(m0 + lr) * K + lk;
    const float* Wp = W + (size_t)(n0 + lr) * K + lk;
    float acc[4][4] = {};
    for (int k0 = 0; k0 < K; k0 += 16) {
        float4 a4 = *(const float4*)(Ap + k0);
        float4 w4 = *(const float4*)(Wp + k0);
        __syncthreads();
        As[lk + 0][lr] = a4.x; As[lk + 1][lr] = a4.y;
        As[lk + 2][lr] = a4.z; As[lk + 3][lr] = a4.w;
        Ws[lk + 0][lr] = w4.x; Ws[lk + 1][lr] = w4.y;
        Ws[lk + 2][lr] = w4.z; Ws[lk + 3][lr] = w4.w;
        __syncthreads();
#pragma unroll
        for (int kk = 0; kk < 16; ++kk) {
            float4 av = *(const float4*)&As[kk][ty << 2];
            float4 wv = *(const float4*)&Ws[kk][tx << 2];
            float a[4] = {av.x, av.y, av.z, av.w};
            float w[4] = {wv.x, wv.y, wv.z, wv.w};
#pragma unroll
            for (int i = 0; i < 4; ++i)
#pragma unroll
                for (int j = 0; j < 4; ++j)
                    acc[i][j] = fmaf(a[i], w[j], acc[i][j]);
        }
    }
#pragma unroll
    for (int i = 0; i < 4; ++i) {
        int row = m0 + (ty << 2) + i;
        int col = n0 + (tx << 2);
        float4 v = make_float4(acc[i][0], acc[i][1], acc[i][2], acc[i][3]);
        if (bias) {
            float4 b4 = *(const float4*)(bias + col);
            v.x += b4.x; v.y += b4.y; v.z += b4.z; v.w += b4.w;
        }
        if (resid) {
            float4 r4 = *(const float4*)(resid + (size_t)row * N + col);
            v.x += r4.x; v.y += r4.y; v.z += r4.z; v.w += r4.w;
        }
        *(float4*)(C + (size_t)row * N + col) = v;
    }
}

// ---------------------------------------------------------------------------
// RoPE in-place on q (12 heads) and k (4 heads) per token
// ---------------------------------------------------------------------------
__global__ __launch_bounds__(256)
void rope_kernel(float* __restrict__ Q, float* __restrict__ Kb,
                 const int* __restrict__ pos_ids) {
    const int t = blockIdx.x;
    const float pos = (float)pos_ids[t];
    const int tid = threadIdx.x;
#pragma unroll
    for (int it = 0; it < 2; ++it) {
        int p = tid + (it << 8);
        int head = p >> 5, i = p & 31;
        float invf = expf(-(float)i * 0.28782313662425572f); // ln(1e4)/32
        float ang = pos * invf;
        float c = cosf(ang), sn = sinf(ang);
        float* base = (head < NHEAD)
            ? (Q + (size_t)t * HID + head * HDIM)
            : (Kb + (size_t)t * (KVHEAD * HDIM) + (head - NHEAD) * HDIM);
        float x1 = base[i], x2 = base[i + 32];
        base[i]      = x1 * c - x2 * sn;
        base[i + 32] = x2 * c + x1 * sn;
    }
}

// ---------------------------------------------------------------------------
// Self attention (causal GQA). Block: 256 thr = 16 queries x 16 lanes.
// Grid: (SEQ/16, NHEAD, BATCH). Scores kept in registers (<=8 tiles x 4).
// ---------------------------------------------------------------------------
__global__ __launch_bounds__(256)
void attn_self(const float* __restrict__ Q, const float* __restrict__ K,
               const float* __restrict__ V, const float* __restrict__ mask,
               float* __restrict__ O) {
    const int qt = blockIdx.x, n = blockIdx.y, b = blockIdx.z;
    const int kv = n / REP;
    const int tid = threadIdx.x;
    const int qi = tid >> 4, li = tid & 15;
    __shared__ float4 Qs[16][17];
    __shared__ float4 KVs[64][17];
    __shared__ float Ps[16][64];
    const int q0 = qt << 4;
    Qs[qi][li] = *(const float4*)(Q + (size_t)(b * SEQ + q0 + qi) * HID
                                  + n * HDIM + (li << 2));
    const int nt = (q0 + 15) / 64 + 1;
    float sc[8][4];
    const float scale = 0.125f;
    for (int t = 0; t < nt; ++t) {
        __syncthreads();
#pragma unroll
        for (int it = 0; it < 4; ++it) {
            int id = tid + (it << 8);
            int row = id >> 4, c4 = id & 15;
            KVs[row][c4] = *(const float4*)(K + (size_t)(b * SEQ + (t << 6) + row)
                                            * (KVHEAD * HDIM) + kv * HDIM + (c4 << 2));
        }
        __syncthreads();
        float a0 = 0, a1 = 0, a2 = 0, a3 = 0;
#pragma unroll
        for (int d4 = 0; d4 < 16; ++d4) {
            float4 q4 = Qs[qi][d4];
            float4 k0v = KVs[(li << 2) + 0][d4];
            float4 k1v = KVs[(li << 2) + 1][d4];
            float4 k2v = KVs[(li << 2) + 2][d4];
            float4 k3v = KVs[(li << 2) + 3][d4];
            a0 += q4.x * k0v.x + q4.y * k0v.y + q4.z * k0v.z + q4.w * k0v.w;
            a1 += q4.x * k1v.x + q4.y * k1v.y + q4.z * k1v.z + q4.w * k1v.w;
            a2 += q4.x * k2v.x + q4.y * k2v.y + q4.z * k2v.z + q4.w * k2v.w;
            a3 += q4.x * k3v.x + q4.y * k3v.y + q4.z * k3v.z + q4.w * k3v.w;
        }
        const float* mrow = mask + (size_t)(q0 + qi) * SEQ + (t << 6) + (li << 2);
        sc[t][0] = a0 * scale + mrow[0];
        sc[t][1] = a1 * scale + mrow[1];
        sc[t][2] = a2 * scale + mrow[2];
        sc[t][3] = a3 * scale + mrow[3];
    }
    float m = -3.4e38f;
    for (int t = 0; t < nt; ++t)
#pragma unroll
        for (int j = 0; j < 4; ++j) m = fmaxf(m, sc[t][j]);
    for (int x = 1; x < 16; x <<= 1) m = fmaxf(m, __shfl_xor(m, x));
    float l = 0;
    for (int t = 0; t < nt; ++t)
#pragma unroll
        for (int j = 0; j < 4; ++j) {
            float p = __expf(sc[t][j] - m);
            sc[t][j] = p;
            l += p;
        }
    for (int x = 1; x < 16; x <<= 1) l += __shfl_xor(l, x);
    float o0 = 0, o1 = 0, o2 = 0, o3 = 0;
    for (int t = 0; t < nt; ++t) {
        __syncthreads();
#pragma unroll
        for (int it = 0; it < 4; ++it) {
            int id = tid + (it << 8);
            int row = id >> 4, c4 = id & 15;
            KVs[row][c4] = *(const float4*)(V + (size_t)(b * SEQ + (t << 6) + row)
                                            * (KVHEAD * HDIM) + kv * HDIM + (c4 << 2));
        }
        Ps[qi][(li << 2) + 0] = sc[t][0];
        Ps[qi][(li << 2) + 1] = sc[t][1];
        Ps[qi][(li << 2) + 2] = sc[t][2];
        Ps[qi][(li << 2) + 3] = sc[t][3];
        __syncthreads();
#pragma unroll
        for (int j = 0; j < 64; ++j) {
            float p = Ps[qi][j];
            float4 v4 = KVs[j][li];
            o0 = fmaf(p, v4.x, o0);
            o1 = fmaf(p, v4.y, o1);
            o2 = fmaf(p, v4.z, o2);
            o3 = fmaf(p, v4.w, o3);
        }
    }
    float inv = 1.0f / l;
    *(float4*)(O + (size_t)(b * SEQ + q0 + qi) * HID + n * HDIM + (li << 2)) =
        make_float4(o0 * inv, o1 * inv, o2 * inv, o3 * inv);
}

// ---------------------------------------------------------------------------
// Group attention: MHA across the 8 channels. One wave per (s, head).
// ---------------------------------------------------------------------------
__global__ __launch_bounds__(64)
void attn_group(const float* __restrict__ Q, const float* __restrict__ K,
                const float* __restrict__ V, const float* __restrict__ gmask,
                float* __restrict__ O) {
    const int n = blockIdx.x % NHEAD;
    const int s = blockIdx.x / NHEAD;
    const int kv = n / REP;
    const int lane = threadIdx.x;
    __shared__ float Qs[8][65], Ks[8][65], Vs[8][65], Ps[64];
    for (int c = 0; c < 8; ++c) {
        Qs[c][lane] = Q[(size_t)(c * SEQ + s) * HID + n * HDIM + lane];
        Ks[c][lane] = K[(size_t)(c * SEQ + s) * (KVHEAD * HDIM) + kv * HDIM + lane];
        Vs[c][lane] = V[(size_t)(c * SEQ + s) * (KVHEAD * HDIM) + kv * HDIM + lane];
    }
    __syncthreads();
    const int qb = lane >> 3, kb = lane & 7;
    float sc = 0;
    for (int d = 0; d < 64; ++d) sc += Qs[qb][d] * Ks[kb][d];
    sc = sc * 0.125f + gmask[(size_t)s * 64 + qb * 8 + kb];
    float m = sc;
    for (int x = 1; x < 8; x <<= 1) m = fmaxf(m, __shfl_xor(m, x));
    float p = __expf(sc - m);
    float l = p;
    for (int x = 1; x < 8; x <<= 1) l += __shfl_xor(l, x);
    Ps[lane] = p / l;
    __syncthreads();
    for (int q2 = 0; q2 < 8; ++q2) {
        float o = 0;
        for (int c = 0; c < 8; ++c) o += Ps[q2 * 8 + c] * Vs[c][lane];
        O[(size_t)(q2 * SEQ + s) * HID + n * HDIM + lane] = o;
    }
}

// ---------------------------------------------------------------------------
// MoE router: softmax over 8 logits, top-2 (not renormalized), atomic counts
// ---------------------------------------------------------------------------
__global__ __launch_bounds__(64)
void router_kernel(const float* __restrict__ X, const float* __restrict__ GW,
                   int* __restrict__ counts, int* __restrict__ topi,
                   float* __restrict__ topw, int* __restrict__ posb) {
    const int t = blockIdx.x;
    const int lane = threadIdx.x;
    const int e = lane >> 3, c = lane & 7;
    const float4* x4 = (const float4*)(X + (size_t)t * HID + c * 96);
    const float4* g4 = (const float4*)(GW + (size_t)e * HID + c * 96);
    float p = 0;
#pragma unroll
    for (int i = 0; i < 24; ++i) {
        float4 xv = x4[i], gv = g4[i];
        p += xv.x * gv.x + xv.y * gv.y + xv.z * gv.z + xv.w * gv.w;
    }
    p += __shfl_xor(p, 1);
    p += __shfl_xor(p, 2);
    p += __shfl_xor(p, 4);
    float lg[8];
#pragma unroll
    for (int i = 0; i < 8; ++i) lg[i] = __shfl(p, i * 8);
    float m = lg[0];
#pragma unroll
    for (int i = 1; i < 8; ++i) m = fmaxf(m, lg[i]);
    float s = 0;
#pragma unroll
    for (int i = 0; i < 8; ++i) { lg[i] = expf(lg[i] - m); s += lg[i]; }
    float inv = 1.0f / s;
    int i1 = 0; float b1 = lg[0];
#pragma unroll
    for (int i = 1; i < 8; ++i) if (lg[i] > b1) { b1 = lg[i]; i1 = i; }
    int i2 = -1; float b2 = -1.0f;
#pragma unroll
    for (int i = 0; i < 8; ++i)
        if (i != i1 && lg[i] > b2) { b2 = lg[i]; i2 = i; }
    if (lane == 0) {
        topi[t * 2] = i1; topi[t * 2 + 1] = i2;
        topw[t * 2] = b1 * inv; topw[t * 2 + 1] = b2 * inv;
        posb[t * 2] = atomicAdd(&counts[i1], 1);
        posb[t * 2 + 1] = atomicAdd(&counts[i2], 1);
    }
}

__global__ void scan_kernel(const int* __restrict__ counts, int* __restrict__ offsets) {
    int acc = 0;
    for (int e = 0; e < NEXP; ++e) { offsets[e] = acc; acc += counts[e]; }
}

__global__ __launch_bounds__(256)
void fill_slots(const int* __restrict__ topi, const float* __restrict__ topw,
                const int* __restrict__ posb, const int* __restrict__ offsets,
                int* __restrict__ slot_token, float* __restrict__ slot_w,
                int* __restrict__ token_slot) {
    int t = blockIdx.x * 256 + threadIdx.x;
    if (t >= NTOK) return;
#pragma unroll
    for (int k = 0; k < TOPK; ++k) {
        int e = topi[t * 2 + k];
        int sl = offsets[e] + posb[t * 2 + k];
        slot_token[sl] = t;
        slot_w[sl] = topw[t * 2 + k];
        token_slot[t * 2 + k] = sl;
    }
}

// ---------------------------------------------------------------------------
// MoE grouped dual GEMM: H[slot, n] = silu(x@Wg) * (x@Wu). NN layout weights.
// Grid: (IEXP/64, maxM/64, NEXP)
// ---------------------------------------------------------------------------
__global__ __launch_bounds__(256)
void moe_gate_up(const float* __restrict__ X, const float* __restrict__ Wg,
                 const float* __restrict__ Wu,
                 const int* __restrict__ slot_token, const int* __restrict__ counts,
                 const int* __restrict__ offsets, float* __restrict__ H) {
    const int e = blockIdx.z;
    const int Ce = counts[e];
    const int m0 = blockIdx.y << 6;
    if (m0 >= Ce) return;
    const int n0 = blockIdx.x << 6;
    const int base = offsets[e];
    __shared__ float As[16][68];
    __shared__ float Gs[16][68];
    __shared__ float Us[16][68];
    const int tid = threadIdx.x;
    const int tx = tid & 15, ty = tid >> 4;
    const int lr = tid >> 2, lk = (tid & 3) << 2;
    int arow = m0 + lr; if (arow >= Ce) arow = Ce - 1;
    const float* Ap = X + (size_t)slot_token[base + arow] * HID + lk;
    const int wk = tid >> 4;
    const int wn = (tid & 15) << 2;
    const float* Gp = Wg + (size_t)e * HID * IEXP + (size_t)wk * IEXP + n0 + wn;
    const float* Up = Wu + (size_t)e * HID * IEXP + (size_t)wk * IEXP + n0 + wn;
    float accg[4][4] = {}, accu[4][4] = {};
    for (int k0 = 0; k0 < HID; k0 += 16) {
        float4 a4 = *(const float4*)(Ap + k0);
        float4 g4 = *(const float4*)(Gp + (size_t)k0 * IEXP);
        float4 u4 = *(const float4*)(Up + (size_t)k0 * IEXP);
        __syncthreads();
        As[lk + 0][lr] = a4.x; As[lk + 1][lr] = a4.y;
        As[lk + 2][lr] = a4.z; As[lk + 3][lr] = a4.w;
        *(float4*)&Gs[wk][wn] = g4;
        *(float4*)&Us[wk][wn] = u4;
        __syncthreads();
#pragma unroll
        for (int kk = 0; kk < 16; ++kk) {
            float4 av = *(const float4*)&As[kk][ty << 2];
            float4 gv = *(const float4*)&Gs[kk][tx << 2];
            float4 uv = *(const float4*)&Us[kk][tx << 2];
            float a[4] = {av.x, av.y, av.z, av.w};
            float g[4] = {gv.x, gv.y, gv.z, gv.w};
            float u[4] = {uv.x, uv.y, uv.z, uv.w};
#pragma unroll
            for (int i = 0; i < 4; ++i)
#pragma unroll
                for (int j = 0; j < 4; ++j) {
                    accg[i][j] = fmaf(a[i], g[j], accg[i][j]);
                    accu[i][j] = fmaf(a[i], u[j], accu[i][j]);
                }
        }
    }
#pragma unroll
    for (int i = 0; i < 4; ++i) {
        int row = m0 + (ty << 2) + i;
        if (row >= Ce) continue;
        size_t sl = (size_t)(base + row);
        float4 hv;
        float g0 = accg[i][0], g1 = accg[i][1], g2 = accg[i][2], g3 = accg[i][3];
        hv.x = g0 / (1.0f + __expf(-g0)) * accu[i][0];
        hv.y = g1 / (1.0f + __expf(-g1)) * accu[i][1];
        hv.z = g2 / (1.0f + __expf(-g2)) * accu[i][2];
        hv.w = g3 / (1.0f + __expf(-g3)) * accu[i][3];
        *(float4*)(H + sl * IEXP + n0 + (tx << 2)) = hv;
    }
}

// ---------------------------------------------------------------------------
// MoE grouped down GEMM: D[slot, n] = slot_w * (H @ Wd). Grid (HID/64, maxM/64, E)
// ---------------------------------------------------------------------------
__global__ __launch_bounds__(256)
void moe_down(const float* __restrict__ H, const float* __restrict__ Wd,
              const float* __restrict__ slot_w, const int* __restrict__ counts,
              const int* __restrict__ offsets, float* __restrict__ D) {
    const int e = blockIdx.z;
    const int Ce = counts[e];
    const int m0 = blockIdx.y << 6;
    if (m0 >= Ce) return;
    const int n0 = blockIdx.x << 6;
    const int base = offsets[e];
    __shared__ float As[16][68];
    __shared__ float Ws[16][68];
    const int tid = threadIdx.x;
    const int tx = tid & 15, ty = tid >> 4;
    const int lr = tid >> 2, lk = (tid & 3) << 2;
    int arow = m0 + lr; if (arow >= Ce) arow = Ce - 1;
    const float* Ap = H + (size_t)(base + arow) * IEXP + lk;
    const int wk = tid >> 4;
    const int wn = (tid & 15) << 2;
    const float* Wp = Wd + (size_t)e * IEXP * HID + (size_t)wk * HID + n0 + wn;
    float acc[4][4] = {};
    for (int k0 = 0; k0 < IEXP; k0 += 16) {
        float4 a4 = *(const float4*)(Ap + k0);
        float4 w4 = *(const float4*)(Wp + (size_t)k0 * HID);
        __syncthreads();
        As[lk + 0][lr] = a4.x; As[lk + 1][lr] = a4.y;
        As[lk + 2][lr] = a4.z; As[lk + 3][lr] = a4.w;
        *(float4*)&Ws[wk][wn] = w4;
        __syncthreads();
#pragma unroll
        for (int kk = 0; kk < 16; ++kk) {
            float4 av = *(const float4*)&As[kk][ty << 2];
            float4 wv = *(const float4*)&Ws[kk][tx << 2];
            float a[4] = {av.x, av.y, av.z, av.w};
            float w[4] = {wv.x, wv.y, wv.z, wv.w};
#pragma unroll
            for (int i = 0; i < 4; ++i)
#pragma unroll
                for (int j = 0; j < 4; ++j)
                    acc[i][j] = fmaf(a[i], w[j], acc[i][j]);
        }
    }
#pragma unroll
    for (int i = 0; i < 4; ++i) {
        int row = m0 + (ty << 2) + i;
        if (row >= Ce) continue;
        size_t sl = (size_t)(base + row);
        float sw = slot_w[sl];
        float4 v = make_float4(acc[i][0] * sw, acc[i][1] * sw,
                               acc[i][2] * sw, acc[i][3] * sw);
        *(float4*)(D + sl * HID + n0 + (tx << 2)) = v;
    }
}

__global__ __launch_bounds__(256)
void moe_add(float* __restrict__ out, const float* __restrict__ D,
             const int* __restrict__ token_slot) {
    const int t = blockIdx.y;
    const int h = blockIdx.x * 256 + threadIdx.x;
    int s0 = token_slot[t * 2], s1 = token_slot[t * 2 + 1];
    out[(size_t)t * HID + h] += D[(size_t)s0 * HID + h] + D[(size_t)s1 * HID + h];
}

// ---------------------------------------------------------------------------
extern "C" void kernel_launch(void* const* d_in, const int* in_sizes, int n_in,
                              void* d_out, int out_size, void* d_ws, size_t ws_size,
                              hipStream_t stream) {
    const float* hidden = (const float*)d_in[0];
    const float* amask  = (const float*)d_in[1];
    const float* gmask  = (const float*)d_in[2];
    const int*   posids = (const int*)d_in[3];
    const float* ln1 = (const float*)d_in[4];
    const float* ln2 = (const float*)d_in[5];
    const float* ln3 = (const float*)d_in[6];
    const float* sqw = (const float*)d_in[7];  const float* sqb = (const float*)d_in[8];
    const float* skw = (const float*)d_in[9];  const float* skb = (const float*)d_in[10];
    const float* svw = (const float*)d_in[11]; const float* svb = (const float*)d_in[12];
    const float* sow = (const float*)d_in[13];
    const float* gqw = (const float*)d_in[14]; const float* gqb = (const float*)d_in[15];
    const float* gkw = (const float*)d_in[16]; const float* gkb = (const float*)d_in[17];
    const float* gvw = (const float*)d_in[18]; const float* gvb = (const float*)d_in[19];
    const float* gow = (const float*)d_in[20];
    const float* gatew = (const float*)d_in[21];
    const float* wg = (const float*)d_in[22];
    const float* wu = (const float*)d_in[23];
    const float* wd = (const float*)d_in[24];
    float* out = (float*)d_out;

    // workspace carve (fp32) — ~122 MB total
    float* f = (float*)d_ws;
    float* xb   = f; f += (size_t)NTOK * HID;
    float* qb   = f; f += (size_t)NTOK * HID;
    float* kbuf = f; f += (size_t)NTOK * KVHEAD * HDIM;
    float* vbuf = f; f += (size_t)NTOK * KVHEAD * HDIM;
    float* ab   = f; f += (size_t)NTOK * HID;
    float* Hbuf = f; f += (size_t)NSLOT * IEXP;
    float* Dbuf = f; f += (size_t)NSLOT * HID;
    float* slotw = f; f += NSLOT;
    float* topw  = f; f += NSLOT;
    int* ip = (int*)f;
    int* counts  = ip; ip += 8;
    int* offsets = ip; ip += 8;
    int* topi    = ip; ip += NSLOT;
    int* posb    = ip; ip += NSLOT;
    int* slot_token = ip; ip += NSLOT;
    int* token_slot = ip; ip += NSLOT;

    // ---- self attention ----
    rmsnorm_kernel<<<NTOK, 256, 0, stream>>>(hidden, ln1, xb);
    gemm_nt<<<dim3(12, 64), 256, 0, stream>>>(xb, sqw, sqb, nullptr, qb, NTOK, 768, 768);
    gemm_nt<<<dim3(4, 64), 256, 0, stream>>>(xb, skw, skb, nullptr, kbuf, NTOK, 256, 768);
    gemm_nt<<<dim3(4, 64), 256, 0, stream>>>(xb, svw, svb, nullptr, vbuf, NTOK, 256, 768);
    rope_kernel<<<NTOK, 256, 0, stream>>>(qb, kbuf, posids);
    attn_self<<<dim3(SEQ / 16, NHEAD, BATCH), 256, 0, stream>>>(qb, kbuf, vbuf, amask, ab);
    gemm_nt<<<dim3(12, 64), 256, 0, stream>>>(ab, sow, nullptr, hidden, out, NTOK, 768, 768);

    // ---- group attention ----
    rmsnorm_kernel<<<NTOK, 256, 0, stream>>>(out, ln2, xb);
    gemm_nt<<<dim3(12, 64), 256, 0, stream>>>(xb, gqw, gqb, nullptr, qb, NTOK, 768, 768);
    gemm_nt<<<dim3(4, 64), 256, 0, stream>>>(xb, gkw, gkb, nullptr, kbuf, NTOK, 256, 768);
    gemm_nt<<<dim3(4, 64), 256, 0, stream>>>(xb, gvw, gvb, nullptr, vbuf, NTOK, 256, 768);
    attn_group<<<SEQ * NHEAD, 64, 0, stream>>>(qb, kbuf, vbuf, gmask, ab);
    gemm_nt<<<dim3(12, 64), 256, 0, stream>>>(ab, gow, nullptr, out, out, NTOK, 768, 768);

    // ---- MoE ----
    rmsnorm_kernel<<<NTOK, 256, 0, stream>>>(out, ln3, xb);
    hipMemsetAsync(counts, 0, 8 * sizeof(int), stream);
    router_kernel<<<NTOK, 64, 0, stream>>>(xb, gatew, counts, topi, topw, posb);
    scan_kernel<<<1, 1, 0, stream>>>(counts, offsets);
    fill_slots<<<16, 256, 0, stream>>>(topi, topw, posb, offsets,
                                       slot_token, slotw, token_slot);
    moe_gate_up<<<dim3(IEXP / 64, NTOK / 64, NEXP), 256, 0, stream>>>(
        xb, wg, wu, slot_token, counts, offsets, Hbuf);
    moe_down<<<dim3(HID / 64, NTOK / 64, NEXP), 256, 0, stream>>>(
        Hbuf, wd, slotw, counts, offsets, Dbuf);
    moe_add<<<dim3(3, NTOK), 256, 0, stream>>>(out, Dbuf, token_slot);
}

// Round 4
// 1161.917 us; speedup vs baseline: 1.4088x; 1.4088x over previous
//
#include <hip/hip_runtime.h>
#include <math.h>

// Problem constants
#define BATCH 8
#define SEQ 512
#define HID 768
#define NHEAD 12
#define KVHEAD 4
#define HDIM 64
#define NEXP 8
#define TOPK 2
#define IEXP 1536
#define NTOK (BATCH * SEQ)     // 4096
#define NSLOT (NTOK * TOPK)    // 8192
#define REP (NHEAD / KVHEAD)   // 3

typedef unsigned short u16;
typedef float f32x4 __attribute__((ext_vector_type(4)));
typedef __bf16 bf16x8 __attribute__((ext_vector_type(8)));
typedef unsigned short u16x8 __attribute__((ext_vector_type(8)));

__device__ __forceinline__ u16 f2bf(float f) {
    unsigned u = __float_as_uint(f);
    u += 0x7fffu + ((u >> 16) & 1u);   // RNE
    return (u16)(u >> 16);
}

__device__ __forceinline__ void gload16(const void* g, void* l) {
    __builtin_amdgcn_global_load_lds(
        (const __attribute__((address_space(1))) void*)g,
        (__attribute__((address_space(3))) void*)l, 16, 0, 0);
}

// split 8 fp32 -> hi/lo bf16
__device__ __forceinline__ void cvt8(float4 a, float4 b, u16x8& hi, u16x8& lo) {
    float x[8] = {a.x, a.y, a.z, a.w, b.x, b.y, b.z, b.w};
#pragma unroll
    for (int i = 0; i < 8; ++i) {
        u16 h = f2bf(x[i]);
        hi[i] = h;
        lo[i] = f2bf(x[i] - __uint_as_float(((unsigned)h) << 16));
    }
}

// ---------------------------------------------------------------------------
// per-expert transpose + convert: src[e][R][C] fp32 -> dst[e][C][R] bf16
// ---------------------------------------------------------------------------
__global__ __launch_bounds__(256)
void transpose_cvt(const float* __restrict__ src, u16* __restrict__ dst,
                   int R, int C) {
    const int e = blockIdx.z;
    src += (size_t)e * R * C;
    dst += (size_t)e * R * C;
    __shared__ float t[32][33];
    const int c0 = blockIdx.x << 5, r0 = blockIdx.y << 5;
    const int tx = threadIdx.x, ty = threadIdx.y;
#pragma unroll
    for (int i = 0; i < 4; ++i)
        t[ty * 4 + i][tx] = src[(size_t)(r0 + ty * 4 + i) * C + c0 + tx];
    __syncthreads();
#pragma unroll
    for (int i = 0; i < 4; ++i)
        dst[(size_t)(c0 + ty * 4 + i) * R + r0 + tx] = f2bf(t[tx][ty * 4 + i]);
}

// ---------------------------------------------------------------------------
// RMSNorm: one block per token (fp32 out)
// ---------------------------------------------------------------------------
__global__ __launch_bounds__(256)
void rmsnorm_kernel(const float* __restrict__ X, const float* __restrict__ W,
                    float* __restrict__ Y) {
    const int t = blockIdx.x;
    const int tid = threadIdx.x;
    const float* x = X + (size_t)t * HID;
    float x0 = x[tid], x1 = x[tid + 256], x2 = x[tid + 512];
    float ss = x0 * x0 + x1 * x1 + x2 * x2;
    for (int m = 1; m < 64; m <<= 1) ss += __shfl_xor(ss, m);
    __shared__ float red[4];
    if ((tid & 63) == 0) red[tid >> 6] = ss;
    __syncthreads();
    float tot = red[0] + red[1] + red[2] + red[3];
    float inv = rsqrtf(tot * (1.0f / HID) + 1e-6f);
    float* y = Y + (size_t)t * HID;
    y[tid]       = x0 * inv * W[tid];
    y[tid + 256] = x1 * inv * W[tid + 256];
    y[tid + 512] = x2 * inv * W[tid + 512];
}

// ---------------------------------------------------------------------------
// fp32 NT GEMM mainloop pieces. Tile 128x128, BK=16, 256 thr, 8x8 acc/thread.
// Row split per thread: {ty*4..+3} U {64+ty*4..+3}; cols analogous with tx.
// ---------------------------------------------------------------------------
#define F32_GEMM_BODY(KDIM)                                                   \
    const int tid = threadIdx.x;                                              \
    const int tx = tid & 15, ty = tid >> 4;                                   \
    const int lr = tid >> 2, kq = (tid & 3) << 2;                             \
    __shared__ float As[16][132];                                             \
    __shared__ float Bs[16][132];                                             \
    float acc[8][8] = {};                                                     \
    for (int k0 = 0; k0 < (KDIM); k0 += 16) {                                 \
        float4 a0 = *(const float4*)(Ap + k0);                                \
        float4 a1 = *(const float4*)(Ap2 + k0);                               \
        float4 b0 = *(const float4*)(Bp + k0);                                \
        float4 b1 = *(const float4*)(Bp2 + k0);                               \
        __syncthreads();                                                      \
        As[kq + 0][lr] = a0.x; As[kq + 1][lr] = a0.y;                         \
        As[kq + 2][lr] = a0.z; As[kq + 3][lr] = a0.w;                         \
        As[kq + 0][64 + lr] = a1.x; As[kq + 1][64 + lr] = a1.y;               \
        As[kq + 2][64 + lr] = a1.z; As[kq + 3][64 + lr] = a1.w;               \
        Bs[kq + 0][lr] = b0.x; Bs[kq + 1][lr] = b0.y;                         \
        Bs[kq + 2][lr] = b0.z; Bs[kq + 3][lr] = b0.w;                         \
        Bs[kq + 0][64 + lr] = b1.x; Bs[kq + 1][64 + lr] = b1.y;               \
        Bs[kq + 2][64 + lr] = b1.z; Bs[kq + 3][64 + lr] = b1.w;               \
        __syncthreads();                                                      \
        _Pragma("unroll")                                                     \
        for (int kk = 0; kk < 16; ++kk) {                                     \
            float4 ra0 = *(const float4*)&As[kk][ty << 2];                    \
            float4 ra1 = *(const float4*)&As[kk][64 + (ty << 2)];             \
            float4 rb0 = *(const float4*)&Bs[kk][tx << 2];                    \
            float4 rb1 = *(const float4*)&Bs[kk][64 + (tx << 2)];             \
            float av[8] = {ra0.x, ra0.y, ra0.z, ra0.w,                        \
                           ra1.x, ra1.y, ra1.z, ra1.w};                       \
            float bv[8] = {rb0.x, rb0.y, rb0.z, rb0.w,                        \
                           rb1.x, rb1.y, rb1.z, rb1.w};                       \
            _Pragma("unroll")                                                 \
            for (int i = 0; i < 8; ++i)                                       \
                _Pragma("unroll")                                             \
                for (int j = 0; j < 8; ++j)                                   \
                    acc[i][j] = fmaf(av[i], bv[j], acc[i][j]);                \
        }                                                                     \
    }

// Fused QKV projection, fp32. Grid (10, 32).
__global__ __launch_bounds__(256)
void qkv_f32(const float* __restrict__ X,
             const float* __restrict__ Wq, const float* __restrict__ Wk,
             const float* __restrict__ Wv,
             const float* __restrict__ bq, const float* __restrict__ bk,
             const float* __restrict__ bv,
             float* __restrict__ Qo, float* __restrict__ Ko,
             float* __restrict__ Vo) {
    const int m0 = blockIdx.y << 7, n0 = blockIdx.x << 7;
    const float* Wbase; int nb;
    if (n0 < 768)       { Wbase = Wq; nb = n0; }
    else if (n0 < 1024) { Wbase = Wk; nb = n0 - 768; }
    else                { Wbase = Wv; nb = n0 - 1024; }
    {
        const int tid = threadIdx.x;
        const int lr_ = tid >> 2;
        (void)lr_;
    }
    const int tid0 = threadIdx.x;
    const int lr0 = tid0 >> 2, kq0 = (tid0 & 3) << 2;
    const float* Ap  = X + (size_t)(m0 + lr0) * HID + kq0;
    const float* Ap2 = Ap + (size_t)64 * HID;
    const float* Bp  = Wbase + (size_t)(nb + lr0) * HID + kq0;
    const float* Bp2 = Bp + (size_t)64 * HID;
    F32_GEMM_BODY(HID)
    float* outp; const float* bp; int ldc, nl;
    if (n0 < 768)       { outp = Qo; bp = bq; ldc = 768; nl = n0; }
    else if (n0 < 1024) { outp = Ko; bp = bk; ldc = 256; nl = n0 - 768; }
    else                { outp = Vo; bp = bv; ldc = 256; nl = n0 - 1024; }
#pragma unroll
    for (int ri = 0; ri < 8; ++ri) {
        int row = m0 + (ri < 4 ? (ty << 2) + ri : 64 + (ty << 2) + ri - 4);
#pragma unroll
        for (int ch = 0; ch < 2; ++ch) {
            int col = nl + ch * 64 + (tx << 2);
            float4 bb = *(const float4*)(bp + col);
            float4 v = make_float4(acc[ri][ch * 4 + 0] + bb.x,
                                   acc[ri][ch * 4 + 1] + bb.y,
                                   acc[ri][ch * 4 + 2] + bb.z,
                                   acc[ri][ch * 4 + 3] + bb.w);
            *(float4*)(outp + (size_t)row * ldc + col) = v;
        }
    }
}

// Generic fp32 NT GEMM with residual: C = A@W^T + resid. K=N=768 here.
__global__ __launch_bounds__(256)
void gemm_f32(const float* __restrict__ A, const float* __restrict__ W,
              const float* __restrict__ resid, float* __restrict__ C,
              int M, int N, int K) {
    const int m0 = blockIdx.y << 7, n0 = blockIdx.x << 7;
    const int tid0 = threadIdx.x;
    const int lr0 = tid0 >> 2, kq0 = (tid0 & 3) << 2;
    const float* Ap  = A + (size_t)(m0 + lr0) * K + kq0;
    const float* Ap2 = Ap + (size_t)64 * K;
    const float* Bp  = W + (size_t)(n0 + lr0) * K + kq0;
    const float* Bp2 = Bp + (size_t)64 * K;
    F32_GEMM_BODY(K)
#pragma unroll
    for (int ri = 0; ri < 8; ++ri) {
        int row = m0 + (ri < 4 ? (ty << 2) + ri : 64 + (ty << 2) + ri - 4);
#pragma unroll
        for (int ch = 0; ch < 2; ++ch) {
            int col = n0 + ch * 64 + (tx << 2);
            float4 r4 = *(const float4*)(resid + (size_t)row * N + col);
            float4 v = make_float4(acc[ri][ch * 4 + 0] + r4.x,
                                   acc[ri][ch * 4 + 1] + r4.y,
                                   acc[ri][ch * 4 + 2] + r4.z,
                                   acc[ri][ch * 4 + 3] + r4.w);
            *(float4*)(C + (size_t)row * N + col) = v;
        }
    }
}

// ---------------------------------------------------------------------------
// RoPE in-place on q (12 heads) and k (4 heads) per token
// ---------------------------------------------------------------------------
__global__ __launch_bounds__(256)
void rope_kernel(float* __restrict__ Q, float* __restrict__ Kb,
                 const int* __restrict__ pos_ids) {
    const int t = blockIdx.x;
    const float pos = (float)pos_ids[t];
    const int tid = threadIdx.x;
#pragma unroll
    for (int it = 0; it < 2; ++it) {
        int p = tid + (it << 8);
        int head = p >> 5, i = p & 31;
        float invf = expf(-(float)i * 0.28782313662425572f); // ln(1e4)/32
        float ang = pos * invf;
        float c = cosf(ang), sn = sinf(ang);
        float* base = (head < NHEAD)
            ? (Q + (size_t)t * HID + head * HDIM)
            : (Kb + (size_t)t * (KVHEAD * HDIM) + (head - NHEAD) * HDIM);
        float x1 = base[i], x2 = base[i + 32];
        base[i]      = x1 * c - x2 * sn;
        base[i + 32] = x2 * c + x1 * sn;
    }
}

// ---------------------------------------------------------------------------
// Self attention (causal GQA), fp32. 16 queries x 16 lanes per block.
// ---------------------------------------------------------------------------
__global__ __launch_bounds__(256)
void attn_self(const float* __restrict__ Q, const float* __restrict__ K,
               const float* __restrict__ V, const float* __restrict__ mask,
               float* __restrict__ O) {
    const int qt = blockIdx.x, n = blockIdx.y, b = blockIdx.z;
    const int kv = n / REP;
    const int tid = threadIdx.x;
    const int qi = tid >> 4, li = tid & 15;
    __shared__ float4 Qs[16][17];
    __shared__ float4 KVs[64][17];
    __shared__ float Ps[16][64];
    const int q0 = qt << 4;
    Qs[qi][li] = *(const float4*)(Q + (size_t)(b * SEQ + q0 + qi) * HID
                                  + n * HDIM + (li << 2));
    const int nt = (q0 + 15) / 64 + 1;
    float sc[8][4];
    const float scale = 0.125f;
    for (int t = 0; t < nt; ++t) {
        __syncthreads();
#pragma unroll
        for (int it = 0; it < 4; ++it) {
            int id = tid + (it << 8);
            int row = id >> 4, c4 = id & 15;
            KVs[row][c4] = *(const float4*)(K + (size_t)(b * SEQ + (t << 6) + row)
                                            * (KVHEAD * HDIM) + kv * HDIM + (c4 << 2));
        }
        __syncthreads();
        float a0 = 0, a1 = 0, a2 = 0, a3 = 0;
#pragma unroll
        for (int d4 = 0; d4 < 16; ++d4) {
            float4 q4 = Qs[qi][d4];
            float4 k0v = KVs[(li << 2) + 0][d4];
            float4 k1v = KVs[(li << 2) + 1][d4];
            float4 k2v = KVs[(li << 2) + 2][d4];
            float4 k3v = KVs[(li << 2) + 3][d4];
            a0 += q4.x * k0v.x + q4.y * k0v.y + q4.z * k0v.z + q4.w * k0v.w;
            a1 += q4.x * k1v.x + q4.y * k1v.y + q4.z * k1v.z + q4.w * k1v.w;
            a2 += q4.x * k2v.x + q4.y * k2v.y + q4.z * k2v.z + q4.w * k2v.w;
            a3 += q4.x * k3v.x + q4.y * k3v.y + q4.z * k3v.z + q4.w * k3v.w;
        }
        const float* mrow = mask + (size_t)(q0 + qi) * SEQ + (t << 6) + (li << 2);
        sc[t][0] = a0 * scale + mrow[0];
        sc[t][1] = a1 * scale + mrow[1];
        sc[t][2] = a2 * scale + mrow[2];
        sc[t][3] = a3 * scale + mrow[3];
    }
    float m = -3.4e38f;
    for (int t = 0; t < nt; ++t)
#pragma unroll
        for (int j = 0; j < 4; ++j) m = fmaxf(m, sc[t][j]);
    for (int x = 1; x < 16; x <<= 1) m = fmaxf(m, __shfl_xor(m, x));
    float l = 0;
    for (int t = 0; t < nt; ++t)
#pragma unroll
        for (int j = 0; j < 4; ++j) {
            float p = __expf(sc[t][j] - m);
            sc[t][j] = p;
            l += p;
        }
    for (int x = 1; x < 16; x <<= 1) l += __shfl_xor(l, x);
    float o0 = 0, o1 = 0, o2 = 0, o3 = 0;
    for (int t = 0; t < nt; ++t) {
        __syncthreads();
#pragma unroll
        for (int it = 0; it < 4; ++it) {
            int id = tid + (it << 8);
            int row = id >> 4, c4 = id & 15;
            KVs[row][c4] = *(const float4*)(V + (size_t)(b * SEQ + (t << 6) + row)
                                            * (KVHEAD * HDIM) + kv * HDIM + (c4 << 2));
        }
        Ps[qi][(li << 2) + 0] = sc[t][0];
        Ps[qi][(li << 2) + 1] = sc[t][1];
        Ps[qi][(li << 2) + 2] = sc[t][2];
        Ps[qi][(li << 2) + 3] = sc[t][3];
        __syncthreads();
#pragma unroll
        for (int j = 0; j < 64; ++j) {
            float p = Ps[qi][j];
            float4 v4 = KVs[j][li];
            o0 = fmaf(p, v4.x, o0);
            o1 = fmaf(p, v4.y, o1);
            o2 = fmaf(p, v4.z, o2);
            o3 = fmaf(p, v4.w, o3);
        }
    }
    float inv = 1.0f / l;
    *(float4*)(O + (size_t)(b * SEQ + q0 + qi) * HID + n * HDIM + (li << 2)) =
        make_float4(o0 * inv, o1 * inv, o2 * inv, o3 * inv);
}

// ---------------------------------------------------------------------------
// Group attention: MHA across the 8 channels. One wave per (s, head).
// ---------------------------------------------------------------------------
__global__ __launch_bounds__(64)
void attn_group(const float* __restrict__ Q, const float* __restrict__ K,
                const float* __restrict__ V, const float* __restrict__ gmask,
                float* __restrict__ O) {
    const int n = blockIdx.x % NHEAD;
    const int s = blockIdx.x / NHEAD;
    const int kv = n / REP;
    const int lane = threadIdx.x;
    __shared__ float Qs[8][65], Ks[8][65], Vs[8][65], Ps[64];
    for (int c = 0; c < 8; ++c) {
        Qs[c][lane] = Q[(size_t)(c * SEQ + s) * HID + n * HDIM + lane];
        Ks[c][lane] = K[(size_t)(c * SEQ + s) * (KVHEAD * HDIM) + kv * HDIM + lane];
        Vs[c][lane] = V[(size_t)(c * SEQ + s) * (KVHEAD * HDIM) + kv * HDIM + lane];
    }
    __syncthreads();
    const int qb = lane >> 3, kb = lane & 7;
    float sc = 0;
    for (int d = 0; d < 64; ++d) sc += Qs[qb][d] * Ks[kb][d];
    sc = sc * 0.125f + gmask[(size_t)s * 64 + qb * 8 + kb];
    float m = sc;
    for (int x = 1; x < 8; x <<= 1) m = fmaxf(m, __shfl_xor(m, x));
    float p = __expf(sc - m);
    float l = p;
    for (int x = 1; x < 8; x <<= 1) l += __shfl_xor(l, x);
    Ps[lane] = p / l;
    __syncthreads();
    for (int q2 = 0; q2 < 8; ++q2) {
        float o = 0;
        for (int c = 0; c < 8; ++c) o += Ps[q2 * 8 + c] * Vs[c][lane];
        O[(size_t)(q2 * SEQ + s) * HID + n * HDIM + lane] = o;
    }
}

// ---------------------------------------------------------------------------
// MoE router (fp32)
// ---------------------------------------------------------------------------
__global__ __launch_bounds__(64)
void router_kernel(const float* __restrict__ X, const float* __restrict__ GW,
                   int* __restrict__ counts, int* __restrict__ topi,
                   float* __restrict__ topw, int* __restrict__ posb) {
    const int t = blockIdx.x;
    const int lane = threadIdx.x;
    const int e = lane >> 3, c = lane & 7;
    const float4* x4 = (const float4*)(X + (size_t)t * HID + c * 96);
    const float4* g4 = (const float4*)(GW + (size_t)e * HID + c * 96);
    float p = 0;
#pragma unroll
    for (int i = 0; i < 24; ++i) {
        float4 xv = x4[i], gv = g4[i];
        p += xv.x * gv.x + xv.y * gv.y + xv.z * gv.z + xv.w * gv.w;
    }
    p += __shfl_xor(p, 1);
    p += __shfl_xor(p, 2);
    p += __shfl_xor(p, 4);
    float lg[8];
#pragma unroll
    for (int i = 0; i < 8; ++i) lg[i] = __shfl(p, i * 8);
    float m = lg[0];
#pragma unroll
    for (int i = 1; i < 8; ++i) m = fmaxf(m, lg[i]);
    float s = 0;
#pragma unroll
    for (int i = 0; i < 8; ++i) { lg[i] = expf(lg[i] - m); s += lg[i]; }
    float inv = 1.0f / s;
    int i1 = 0; float b1 = lg[0];
#pragma unroll
    for (int i = 1; i < 8; ++i) if (lg[i] > b1) { b1 = lg[i]; i1 = i; }
    int i2 = -1; float b2 = -1.0f;
#pragma unroll
    for (int i = 0; i < 8; ++i)
        if (i != i1 && lg[i] > b2) { b2 = lg[i]; i2 = i; }
    if (lane == 0) {
        topi[t * 2] = i1; topi[t * 2 + 1] = i2;
        topw[t * 2] = b1 * inv; topw[t * 2 + 1] = b2 * inv;
        posb[t * 2] = atomicAdd(&counts[i1], 1);
        posb[t * 2 + 1] = atomicAdd(&counts[i2], 1);
    }
}

__global__ void scan_kernel(const int* __restrict__ counts, int* __restrict__ offsets) {
    int acc = 0;
    for (int e = 0; e < NEXP; ++e) { offsets[e] = acc; acc += counts[e]; }
}

__global__ __launch_bounds__(256)
void fill_slots(const int* __restrict__ topi, const float* __restrict__ topw,
                const int* __restrict__ posb, const int* __restrict__ offsets,
                int* __restrict__ slot_token, float* __restrict__ slot_w,
                int* __restrict__ token_slot) {
    int t = blockIdx.x * 256 + threadIdx.x;
    if (t >= NTOK) return;
#pragma unroll
    for (int k = 0; k < TOPK; ++k) {
        int e = topi[t * 2 + k];
        int sl = offsets[e] + posb[t * 2 + k];
        slot_token[sl] = t;
        slot_w[sl] = topw[t * 2 + k];
        token_slot[t * 2 + k] = sl;
    }
}

// ---------------------------------------------------------------------------
// MoE gate+up grouped GEMM. A fp32 gathered + split hi/lo; Wg/Wu bf16
// [e][IEXP][HID]. H bf16 out. Grid (12, 32, 8).
// ---------------------------------------------------------------------------
__global__ __launch_bounds__(256)
void moe_gate_up(const float* __restrict__ X, const u16* __restrict__ Wg,
                 const u16* __restrict__ Wu,
                 const int* __restrict__ slot_token,
                 const int* __restrict__ counts,
                 const int* __restrict__ offsets, u16* __restrict__ H) {
    const int e = blockIdx.z;
    const int Ce = counts[e];
    const int m0 = blockIdx.y << 7;
    if (Ce == 0 || m0 >= Ce) return;
    const int n0 = blockIdx.x << 7;
    const int base = offsets[e];
    __shared__ __align__(16) u16 Ah[4096];
    __shared__ __align__(16) u16 Al[4096];
    __shared__ __align__(16) u16 Gs[4096];
    __shared__ __align__(16) u16 Us[4096];
    const int tid = threadIdx.x, l = tid & 63, w = tid >> 6;
    const int wm = w & 1, wn = w >> 1;
    const int sr = l >> 2, sc8 = (l & 3) << 3;
    int r0 = m0 + w * 32 + sr;
    int r1 = r0 + 16;
    int t0 = slot_token[base + min(r0, Ce - 1)];
    int t1 = slot_token[base + min(r1, Ce - 1)];
    const float* gA0 = X + (size_t)t0 * HID + sc8;
    const float* gA1 = X + (size_t)t1 * HID + sc8;
    const u16* Wge = Wg + (size_t)e * IEXP * HID;
    const u16* Wue = Wu + (size_t)e * IEXP * HID;
    const u16* gG0 = Wge + (size_t)(n0 + w * 32 + sr) * HID + sc8;
    const u16* gG1 = gG0 + 16 * HID;
    const u16* gU0 = Wue + (size_t)(n0 + w * 32 + sr) * HID + sc8;
    const u16* gU1 = gU0 + 16 * HID;
    const int aoff0 = (w * 32 + sr) * 32 + sc8, aoff1 = aoff0 + 512;
    u16* lG0 = Gs + w * 1024; u16* lG1 = lG0 + 512;
    u16* lU0 = Us + w * 1024; u16* lU1 = lU0 + 512;
    const int fr = l & 15, fc = (l >> 4) << 3;
    f32x4 accg[4][4], accu[4][4];
#pragma unroll
    for (int i = 0; i < 4; ++i)
#pragma unroll
        for (int j = 0; j < 4; ++j) {
            accg[i][j] = (f32x4){0.f, 0.f, 0.f, 0.f};
            accu[i][j] = (f32x4){0.f, 0.f, 0.f, 0.f};
        }
    for (int k0 = 0; k0 < HID; k0 += 32) {
        float4 a00 = *(const float4*)(gA0 + k0);
        float4 a01 = *(const float4*)(gA0 + k0 + 4);
        float4 a10 = *(const float4*)(gA1 + k0);
        float4 a11 = *(const float4*)(gA1 + k0 + 4);
        gload16(gG0 + k0, lG0);
        gload16(gG1 + k0, lG1);
        gload16(gU0 + k0, lU0);
        gload16(gU1 + k0, lU1);
        u16x8 h0, lo0, h1, lo1;
        cvt8(a00, a01, h0, lo0);
        cvt8(a10, a11, h1, lo1);
        *(u16x8*)(Ah + aoff0) = h0; *(u16x8*)(Al + aoff0) = lo0;
        *(u16x8*)(Ah + aoff1) = h1; *(u16x8*)(Al + aoff1) = lo1;
        __syncthreads();
        bf16x8 ah[4], al[4], gf[4], uf[4];
#pragma unroll
        for (int i = 0; i < 4; ++i) {
            ah[i] = *(const bf16x8*)(Ah + (wm * 64 + i * 16 + fr) * 32 + fc);
            al[i] = *(const bf16x8*)(Al + (wm * 64 + i * 16 + fr) * 32 + fc);
            gf[i] = *(const bf16x8*)(Gs + (wn * 64 + i * 16 + fr) * 32 + fc);
            uf[i] = *(const bf16x8*)(Us + (wn * 64 + i * 16 + fr) * 32 + fc);
        }
#pragma unroll
        for (int mf = 0; mf < 4; ++mf)
#pragma unroll
            for (int nf = 0; nf < 4; ++nf) {
                accg[mf][nf] = __builtin_amdgcn_mfma_f32_16x16x32_bf16(
                    ah[mf], gf[nf], accg[mf][nf], 0, 0, 0);
                accg[mf][nf] = __builtin_amdgcn_mfma_f32_16x16x32_bf16(
                    al[mf], gf[nf], accg[mf][nf], 0, 0, 0);
                accu[mf][nf] = __builtin_amdgcn_mfma_f32_16x16x32_bf16(
                    ah[mf], uf[nf], accu[mf][nf], 0, 0, 0);
                accu[mf][nf] = __builtin_amdgcn_mfma_f32_16x16x32_bf16(
                    al[mf], uf[nf], accu[mf][nf], 0, 0, 0);
            }
        __syncthreads();
    }
    const int er = (l >> 4) << 2, ec = l & 15;
#pragma unroll
    for (int mf = 0; mf < 4; ++mf)
#pragma unroll
        for (int i = 0; i < 4; ++i) {
            int row = m0 + wm * 64 + mf * 16 + er + i;
            if (row >= Ce) continue;
            size_t sl = (size_t)(base + row);
#pragma unroll
            for (int nf = 0; nf < 4; ++nf) {
                int col = n0 + wn * 64 + nf * 16 + ec;
                float g = accg[mf][nf][i];
                float u = accu[mf][nf][i];
                float h = g / (1.0f + __expf(-g)) * u;
                H[sl * IEXP + col] = f2bf(h);
            }
        }
}

// ---------------------------------------------------------------------------
// MoE down grouped GEMM bf16: D[slot][HID] fp32 = slot_w * (H @ Wd^T)
// Wd pre-transposed to [e][HID][IEXP]. Grid (6, 32, 8).
// ---------------------------------------------------------------------------
__global__ __launch_bounds__(256)
void moe_down_bf16(const u16* __restrict__ Hb, const u16* __restrict__ Wd,
                   const float* __restrict__ slot_w,
                   const int* __restrict__ counts,
                   const int* __restrict__ offsets, float* __restrict__ D) {
    const int e = blockIdx.z;
    const int Ce = counts[e];
    const int m0 = blockIdx.y << 7;
    if (Ce == 0 || m0 >= Ce) return;
    const int n0 = blockIdx.x << 7;
    const int base = offsets[e];
    __shared__ __align__(16) u16 As[4096];
    __shared__ __align__(16) u16 Bs[4096];
    const int tid = threadIdx.x, l = tid & 63, w = tid >> 6;
    const int wm = w & 1, wn = w >> 1;
    const int sr = l >> 2, sc = (l & 3) << 3;
    const u16* Ae = Hb + (size_t)base * IEXP;
    int r0 = min(m0 + w * 32 + sr, Ce - 1);
    int r1 = min(m0 + w * 32 + 16 + sr, Ce - 1);
    const u16* gA0 = Ae + (size_t)r0 * IEXP + sc;
    const u16* gA1 = Ae + (size_t)r1 * IEXP + sc;
    const u16* Wde = Wd + (size_t)e * HID * IEXP;
    const u16* gB0 = Wde + (size_t)(n0 + w * 32 + sr) * IEXP + sc;
    const u16* gB1 = gB0 + 16 * IEXP;
    u16* lA0 = As + w * 1024; u16* lA1 = lA0 + 512;
    u16* lB0 = Bs + w * 1024; u16* lB1 = lB0 + 512;
    const int fr = l & 15, fc = (l >> 4) << 3;
    f32x4 acc[4][4];
#pragma unroll
    for (int i = 0; i < 4; ++i)
#pragma unroll
        for (int j = 0; j < 4; ++j) acc[i][j] = (f32x4){0.f, 0.f, 0.f, 0.f};
    for (int k0 = 0; k0 < IEXP; k0 += 32) {
        gload16(gA0 + k0, lA0);
        gload16(gA1 + k0, lA1);
        gload16(gB0 + k0, lB0);
        gload16(gB1 + k0, lB1);
        __syncthreads();
        bf16x8 af[4], bfv[4];
#pragma unroll
        for (int i = 0; i < 4; ++i) {
            af[i]  = *(const bf16x8*)(As + (wm * 64 + i * 16 + fr) * 32 + fc);
            bfv[i] = *(const bf16x8*)(Bs + (wn * 64 + i * 16 + fr) * 32 + fc);
        }
#pragma unroll
        for (int mf = 0; mf < 4; ++mf)
#pragma unroll
            for (int nf = 0; nf < 4; ++nf)
                acc[mf][nf] = __builtin_amdgcn_mfma_f32_16x16x32_bf16(
                    af[mf], bfv[nf], acc[mf][nf], 0, 0, 0);
        __syncthreads();
    }
    const int er = (l >> 4) << 2, ec = l & 15;
#pragma unroll
    for (int mf = 0; mf < 4; ++mf)
#pragma unroll
        for (int i = 0; i < 4; ++i) {
            int row = m0 + wm * 64 + mf * 16 + er + i;
            if (row >= Ce) continue;
            size_t sl = (size_t)(base + row);
            float sw = slot_w[sl];
#pragma unroll
            for (int nf = 0; nf < 4; ++nf) {
                int col = n0 + wn * 64 + nf * 16 + ec;
                D[sl * HID + col] = acc[mf][nf][i] * sw;
            }
        }
}

__global__ __launch_bounds__(256)
void moe_add(float* __restrict__ out, const float* __restrict__ D,
             const int* __restrict__ token_slot) {
    const int t = blockIdx.y;
    const int h = blockIdx.x * 256 + threadIdx.x;
    int s0 = token_slot[t * 2], s1 = token_slot[t * 2 + 1];
    out[(size_t)t * HID + h] += D[(size_t)s0 * HID + h] + D[(size_t)s1 * HID + h];
}

// ---------------------------------------------------------------------------
extern "C" void kernel_launch(void* const* d_in, const int* in_sizes, int n_in,
                              void* d_out, int out_size, void* d_ws, size_t ws_size,
                              hipStream_t stream) {
    const float* hidden = (const float*)d_in[0];
    const float* amask  = (const float*)d_in[1];
    const float* gmask  = (const float*)d_in[2];
    const int*   posids = (const int*)d_in[3];
    const float* ln1 = (const float*)d_in[4];
    const float* ln2 = (const float*)d_in[5];
    const float* ln3 = (const float*)d_in[6];
    const float* sqw = (const float*)d_in[7];  const float* sqb = (const float*)d_in[8];
    const float* skw = (const float*)d_in[9];  const float* skb = (const float*)d_in[10];
    const float* svw = (const float*)d_in[11]; const float* svb = (const float*)d_in[12];
    const float* sow = (const float*)d_in[13];
    const float* gqw = (const float*)d_in[14]; const float* gqb = (const float*)d_in[15];
    const float* gkw = (const float*)d_in[16]; const float* gkb = (const float*)d_in[17];
    const float* gvw = (const float*)d_in[18]; const float* gvb = (const float*)d_in[19];
    const float* gow = (const float*)d_in[20];
    const float* gatew = (const float*)d_in[21];
    const float* wg = (const float*)d_in[22];
    const float* wu = (const float*)d_in[23];
    const float* wd = (const float*)d_in[24];
    float* out = (float*)d_out;

    // ---- workspace carve (byte offsets), ~109.3 MB total ----
    char* base = (char*)d_ws;
    float* xb    = (float*)(base + 0);          // 12,582,912 (live thru MoE gather)
    float* qb    = (float*)(base + 12582912);   // 12,582,912
    float* kbuf  = (float*)(base + 25165824);   //  4,194,304
    float* vbuf  = (float*)(base + 29360128);   //  4,194,304
    float* ab    = (float*)(base + 33554432);   // 12,582,912 -> 46,137,344
    u16*   wgt   = (u16*)  (base + 52428800);   // 18,874,368 -> 71,303,168
    u16*   wut   = (u16*)  (base + 71303168);   // 18,874,368 -> 90,177,536
    u16*   wdt   = (u16*)  (base + 90177536);   // 18,874,368 -> 109,051,904
    float* slotw = (float*)(base + 109051904);
    float* topw  = (float*)(base + 109084672);
    int* counts  = (int*)  (base + 109117440);
    int* offsets = (int*)  (base + 109117696);
    int* topi    = (int*)  (base + 109117952);
    int* posb    = (int*)  (base + 109150720);
    int* slot_token = (int*)(base + 109183488);
    int* token_slot = (int*)(base + 109216256);
    // MoE-phase overlays (qb/kbuf/vbuf/ab + wgt-head dead when used):
    u16*   Hbuf  = (u16*)  (base + 12582912);   // 25,165,824 -> 37,748,736
    float* Dbuf  = (float*)(base + 37748736);   // 25,165,824 -> 62,914,560

    // ---- MoE weight transpose+convert (fp32 inputs every call) ----
    transpose_cvt<<<dim3(48, 24, 8), dim3(32, 8), 0, stream>>>(wg, wgt, HID, IEXP);
    transpose_cvt<<<dim3(48, 24, 8), dim3(32, 8), 0, stream>>>(wu, wut, HID, IEXP);
    transpose_cvt<<<dim3(24, 48, 8), dim3(32, 8), 0, stream>>>(wd, wdt, IEXP, HID);

    // ---- self attention (fp32 path: router-flip safe) ----
    rmsnorm_kernel<<<NTOK, 256, 0, stream>>>(hidden, ln1, xb);
    qkv_f32<<<dim3(10, 32), 256, 0, stream>>>(xb, sqw, skw, svw, sqb, skb, svb,
                                              qb, kbuf, vbuf);
    rope_kernel<<<NTOK, 256, 0, stream>>>(qb, kbuf, posids);
    attn_self<<<dim3(SEQ / 16, NHEAD, BATCH), 256, 0, stream>>>(qb, kbuf, vbuf, amask, ab);
    gemm_f32<<<dim3(6, 32), 256, 0, stream>>>(ab, sow, hidden, out, NTOK, HID, HID);

    // ---- group attention (fp32 path) ----
    rmsnorm_kernel<<<NTOK, 256, 0, stream>>>(out, ln2, xb);
    qkv_f32<<<dim3(10, 32), 256, 0, stream>>>(xb, gqw, gkw, gvw, gqb, gkb, gvb,
                                              qb, kbuf, vbuf);
    attn_group<<<SEQ * NHEAD, 64, 0, stream>>>(qb, kbuf, vbuf, gmask, ab);
    gemm_f32<<<dim3(6, 32), 256, 0, stream>>>(ab, gow, out, out, NTOK, HID, HID);

    // ---- MoE (bf16 MFMA: post-router, flip-free) ----
    rmsnorm_kernel<<<NTOK, 256, 0, stream>>>(out, ln3, xb);
    hipMemsetAsync(counts, 0, 8 * sizeof(int), stream);
    router_kernel<<<NTOK, 64, 0, stream>>>(xb, gatew, counts, topi, topw, posb);
    scan_kernel<<<1, 1, 0, stream>>>(counts, offsets);
    fill_slots<<<16, 256, 0, stream>>>(topi, topw, posb, offsets,
                                       slot_token, slotw, token_slot);
    moe_gate_up<<<dim3(12, 32, 8), 256, 0, stream>>>(
        xb, wgt, wut, slot_token, counts, offsets, Hbuf);
    moe_down_bf16<<<dim3(6, 32, 8), 256, 0, stream>>>(
        Hbuf, wdt, slotw, counts, offsets, Dbuf);
    moe_add<<<dim3(3, NTOK), 256, 0, stream>>>(out, Dbuf, token_slot);
}

// Round 5
// 1099.512 us; speedup vs baseline: 1.4888x; 1.0568x over previous
//
#include <hip/hip_runtime.h>
#include <math.h>

// Problem constants
#define BATCH 8
#define SEQ 512
#define HID 768
#define NHEAD 12
#define KVHEAD 4
#define HDIM 64
#define NEXP 8
#define TOPK 2
#define IEXP 1536
#define NTOK (BATCH * SEQ)     // 4096
#define NSLOT (NTOK * TOPK)    // 8192
#define REP (NHEAD / KVHEAD)   // 3

typedef unsigned short u16;
typedef float f32x4 __attribute__((ext_vector_type(4)));
typedef __bf16 bf16x8 __attribute__((ext_vector_type(8)));
typedef unsigned short u16x8 __attribute__((ext_vector_type(8)));

__device__ __forceinline__ u16 f2bf(float f) {
    unsigned u = __float_as_uint(f);
    u += 0x7fffu + ((u >> 16) & 1u);   // RNE
    return (u16)(u >> 16);
}

__device__ __forceinline__ void gload16(const void* g, void* l) {
    __builtin_amdgcn_global_load_lds(
        (const __attribute__((address_space(1))) void*)g,
        (__attribute__((address_space(3))) void*)l, 16, 0, 0);
}

// split 8 fp32 -> hi/lo bf16
__device__ __forceinline__ void cvt8(float4 a, float4 b, u16x8& hi, u16x8& lo) {
    float x[8] = {a.x, a.y, a.z, a.w, b.x, b.y, b.z, b.w};
#pragma unroll
    for (int i = 0; i < 8; ++i) {
        u16 h = f2bf(x[i]);
        hi[i] = h;
        lo[i] = f2bf(x[i] - __uint_as_float(((unsigned)h) << 16));
    }
}

// ---------------------------------------------------------------------------
// per-expert transpose + convert: src[e][R][C] fp32 -> dst[e][C][R] bf16
// ---------------------------------------------------------------------------
__global__ __launch_bounds__(256)
void transpose_cvt(const float* __restrict__ src, u16* __restrict__ dst,
                   int R, int C) {
    const int e = blockIdx.z;
    src += (size_t)e * R * C;
    dst += (size_t)e * R * C;
    __shared__ float t[32][33];
    const int c0 = blockIdx.x << 5, r0 = blockIdx.y << 5;
    const int tx = threadIdx.x, ty = threadIdx.y;
#pragma unroll
    for (int i = 0; i < 4; ++i)
        t[ty * 4 + i][tx] = src[(size_t)(r0 + ty * 4 + i) * C + c0 + tx];
    __syncthreads();
#pragma unroll
    for (int i = 0; i < 4; ++i)
        dst[(size_t)(c0 + ty * 4 + i) * R + r0 + tx] = f2bf(t[tx][ty * 4 + i]);
}

// ---------------------------------------------------------------------------
// RMSNorm: one block per token (fp32 out)
// ---------------------------------------------------------------------------
__global__ __launch_bounds__(256)
void rmsnorm_kernel(const float* __restrict__ X, const float* __restrict__ W,
                    float* __restrict__ Y) {
    const int t = blockIdx.x;
    const int tid = threadIdx.x;
    const float* x = X + (size_t)t * HID;
    float x0 = x[tid], x1 = x[tid + 256], x2 = x[tid + 512];
    float ss = x0 * x0 + x1 * x1 + x2 * x2;
    for (int m = 1; m < 64; m <<= 1) ss += __shfl_xor(ss, m);
    __shared__ float red[4];
    if ((tid & 63) == 0) red[tid >> 6] = ss;
    __syncthreads();
    float tot = red[0] + red[1] + red[2] + red[3];
    float inv = rsqrtf(tot * (1.0f / HID) + 1e-6f);
    float* y = Y + (size_t)t * HID;
    y[tid]       = x0 * inv * W[tid];
    y[tid + 256] = x1 * inv * W[tid + 256];
    y[tid + 512] = x2 * inv * W[tid + 512];
}

// ---------------------------------------------------------------------------
// fp32 NT GEMM mainloop. Tile 128x128, BK=16, 256 thr, 8x8 acc/thread.
// ---------------------------------------------------------------------------
#define F32_GEMM_BODY(KDIM)                                                   \
    const int tid = threadIdx.x;                                              \
    const int tx = tid & 15, ty = tid >> 4;                                   \
    const int lr = tid >> 2, kq = (tid & 3) << 2;                             \
    __shared__ float As[16][132];                                             \
    __shared__ float Bs[16][132];                                             \
    float acc[8][8] = {};                                                     \
    for (int k0 = 0; k0 < (KDIM); k0 += 16) {                                 \
        float4 a0 = *(const float4*)(Ap + k0);                                \
        float4 a1 = *(const float4*)(Ap2 + k0);                               \
        float4 b0 = *(const float4*)(Bp + k0);                                \
        float4 b1 = *(const float4*)(Bp2 + k0);                               \
        __syncthreads();                                                      \
        As[kq + 0][lr] = a0.x; As[kq + 1][lr] = a0.y;                         \
        As[kq + 2][lr] = a0.z; As[kq + 3][lr] = a0.w;                         \
        As[kq + 0][64 + lr] = a1.x; As[kq + 1][64 + lr] = a1.y;               \
        As[kq + 2][64 + lr] = a1.z; As[kq + 3][64 + lr] = a1.w;               \
        Bs[kq + 0][lr] = b0.x; Bs[kq + 1][lr] = b0.y;                         \
        Bs[kq + 2][lr] = b0.z; Bs[kq + 3][lr] = b0.w;                         \
        Bs[kq + 0][64 + lr] = b1.x; Bs[kq + 1][64 + lr] = b1.y;               \
        Bs[kq + 2][64 + lr] = b1.z; Bs[kq + 3][64 + lr] = b1.w;               \
        __syncthreads();                                                      \
        _Pragma("unroll")                                                     \
        for (int kk = 0; kk < 16; ++kk) {                                     \
            float4 ra0 = *(const float4*)&As[kk][ty << 2];                    \
            float4 ra1 = *(const float4*)&As[kk][64 + (ty << 2)];             \
            float4 rb0 = *(const float4*)&Bs[kk][tx << 2];                    \
            float4 rb1 = *(const float4*)&Bs[kk][64 + (tx << 2)];             \
            float av[8] = {ra0.x, ra0.y, ra0.z, ra0.w,                        \
                           ra1.x, ra1.y, ra1.z, ra1.w};                       \
            float bv[8] = {rb0.x, rb0.y, rb0.z, rb0.w,                        \
                           rb1.x, rb1.y, rb1.z, rb1.w};                       \
            _Pragma("unroll")                                                 \
            for (int i = 0; i < 8; ++i)                                       \
                _Pragma("unroll")                                             \
                for (int j = 0; j < 8; ++j)                                   \
                    acc[i][j] = fmaf(av[i], bv[j], acc[i][j]);                \
        }                                                                     \
    }

// Fused QKV projection, fp32. Grid (10, 32).
__global__ __launch_bounds__(256)
void qkv_f32(const float* __restrict__ X,
             const float* __restrict__ Wq, const float* __restrict__ Wk,
             const float* __restrict__ Wv,
             const float* __restrict__ bq, const float* __restrict__ bk,
             const float* __restrict__ bv,
             float* __restrict__ Qo, float* __restrict__ Ko,
             float* __restrict__ Vo) {
    const int m0 = blockIdx.y << 7, n0 = blockIdx.x << 7;
    const float* Wbase; int nb;
    if (n0 < 768)       { Wbase = Wq; nb = n0; }
    else if (n0 < 1024) { Wbase = Wk; nb = n0 - 768; }
    else                { Wbase = Wv; nb = n0 - 1024; }
    const int tid0 = threadIdx.x;
    const int lr0 = tid0 >> 2, kq0 = (tid0 & 3) << 2;
    const float* Ap  = X + (size_t)(m0 + lr0) * HID + kq0;
    const float* Ap2 = Ap + (size_t)64 * HID;
    const float* Bp  = Wbase + (size_t)(nb + lr0) * HID + kq0;
    const float* Bp2 = Bp + (size_t)64 * HID;
    F32_GEMM_BODY(HID)
    float* outp; const float* bp; int ldc, nl;
    if (n0 < 768)       { outp = Qo; bp = bq; ldc = 768; nl = n0; }
    else if (n0 < 1024) { outp = Ko; bp = bk; ldc = 256; nl = n0 - 768; }
    else                { outp = Vo; bp = bv; ldc = 256; nl = n0 - 1024; }
#pragma unroll
    for (int ri = 0; ri < 8; ++ri) {
        int row = m0 + (ri < 4 ? (ty << 2) + ri : 64 + (ty << 2) + ri - 4);
#pragma unroll
        for (int ch = 0; ch < 2; ++ch) {
            int col = nl + ch * 64 + (tx << 2);
            float4 bb = *(const float4*)(bp + col);
            float4 v = make_float4(acc[ri][ch * 4 + 0] + bb.x,
                                   acc[ri][ch * 4 + 1] + bb.y,
                                   acc[ri][ch * 4 + 2] + bb.z,
                                   acc[ri][ch * 4 + 3] + bb.w);
            *(float4*)(outp + (size_t)row * ldc + col) = v;
        }
    }
}

// Generic fp32 NT GEMM with residual: C = A@W^T + resid.
__global__ __launch_bounds__(256)
void gemm_f32(const float* __restrict__ A, const float* __restrict__ W,
              const float* __restrict__ resid, float* __restrict__ C,
              int M, int N, int K) {
    const int m0 = blockIdx.y << 7, n0 = blockIdx.x << 7;
    const int tid0 = threadIdx.x;
    const int lr0 = tid0 >> 2, kq0 = (tid0 & 3) << 2;
    const float* Ap  = A + (size_t)(m0 + lr0) * K + kq0;
    const float* Ap2 = Ap + (size_t)64 * K;
    const float* Bp  = W + (size_t)(n0 + lr0) * K + kq0;
    const float* Bp2 = Bp + (size_t)64 * K;
    F32_GEMM_BODY(K)
#pragma unroll
    for (int ri = 0; ri < 8; ++ri) {
        int row = m0 + (ri < 4 ? (ty << 2) + ri : 64 + (ty << 2) + ri - 4);
#pragma unroll
        for (int ch = 0; ch < 2; ++ch) {
            int col = n0 + ch * 64 + (tx << 2);
            float4 r4 = *(const float4*)(resid + (size_t)row * N + col);
            float4 v = make_float4(acc[ri][ch * 4 + 0] + r4.x,
                                   acc[ri][ch * 4 + 1] + r4.y,
                                   acc[ri][ch * 4 + 2] + r4.z,
                                   acc[ri][ch * 4 + 3] + r4.w);
            *(float4*)(C + (size_t)row * N + col) = v;
        }
    }
}

// ---------------------------------------------------------------------------
// RoPE in-place on q (12 heads) and k (4 heads) per token
// ---------------------------------------------------------------------------
__global__ __launch_bounds__(256)
void rope_kernel(float* __restrict__ Q, float* __restrict__ Kb,
                 const int* __restrict__ pos_ids) {
    const int t = blockIdx.x;
    const float pos = (float)pos_ids[t];
    const int tid = threadIdx.x;
#pragma unroll
    for (int it = 0; it < 2; ++it) {
        int p = tid + (it << 8);
        int head = p >> 5, i = p & 31;
        float invf = expf(-(float)i * 0.28782313662425572f); // ln(1e4)/32
        float ang = pos * invf;
        float c = cosf(ang), sn = sinf(ang);
        float* base = (head < NHEAD)
            ? (Q + (size_t)t * HID + head * HDIM)
            : (Kb + (size_t)t * (KVHEAD * HDIM) + (head - NHEAD) * HDIM);
        float x1 = base[i], x2 = base[i + 32];
        base[i]      = x1 * c - x2 * sn;
        base[i + 32] = x2 * c + x1 * sn;
    }
}

// ---------------------------------------------------------------------------
// Self attention (causal GQA), fp32. 32 queries x 16 lanes, 512 threads.
// Lane li handles keys {li, li+16, li+32, li+48} of each 64-key tile:
// bank = 4*(li+d4) mod 32 -> 2-way aliasing only (free on CDNA4).
// ---------------------------------------------------------------------------
__global__ __launch_bounds__(512)
void attn_self(const float* __restrict__ Q, const float* __restrict__ K,
               const float* __restrict__ V, const float* __restrict__ mask,
               float* __restrict__ O) {
    const int qt = blockIdx.x, n = blockIdx.y, b = blockIdx.z;
    const int kv = n / REP;
    const int tid = threadIdx.x;
    const int qi = tid >> 4, li = tid & 15;   // qi 0..31, li 0..15
    __shared__ float4 Qs[32][17];
    __shared__ float4 KVs[64][17];
    __shared__ float Ps[32][68];
    const int q0 = qt << 5;
    Qs[qi][li] = *(const float4*)(Q + (size_t)(b * SEQ + q0 + qi) * HID
                                  + n * HDIM + (li << 2));
    const int nt = q0 / 64 + 1;               // tiles of 64 keys (causal)
    float sc[8][4];
    const float scale = 0.125f;
    for (int t = 0; t < nt; ++t) {
        __syncthreads();
#pragma unroll
        for (int it = 0; it < 2; ++it) {
            int id = tid + (it << 9);
            int row = id >> 4, c4 = id & 15;
            KVs[row][c4] = *(const float4*)(K + (size_t)(b * SEQ + (t << 6) + row)
                                            * (KVHEAD * HDIM) + kv * HDIM + (c4 << 2));
        }
        __syncthreads();
        float a0 = 0, a1 = 0, a2 = 0, a3 = 0;
#pragma unroll
        for (int d4 = 0; d4 < 16; ++d4) {
            float4 q4 = Qs[qi][d4];
            float4 k0v = KVs[li +  0][d4];
            float4 k1v = KVs[li + 16][d4];
            float4 k2v = KVs[li + 32][d4];
            float4 k3v = KVs[li + 48][d4];
            a0 += q4.x * k0v.x + q4.y * k0v.y + q4.z * k0v.z + q4.w * k0v.w;
            a1 += q4.x * k1v.x + q4.y * k1v.y + q4.z * k1v.z + q4.w * k1v.w;
            a2 += q4.x * k2v.x + q4.y * k2v.y + q4.z * k2v.z + q4.w * k2v.w;
            a3 += q4.x * k3v.x + q4.y * k3v.y + q4.z * k3v.z + q4.w * k3v.w;
        }
        const float* mrow = mask + (size_t)(q0 + qi) * SEQ + (t << 6);
        sc[t][0] = a0 * scale + mrow[li];
        sc[t][1] = a1 * scale + mrow[li + 16];
        sc[t][2] = a2 * scale + mrow[li + 32];
        sc[t][3] = a3 * scale + mrow[li + 48];
    }
    float m = -3.4e38f;
    for (int t = 0; t < nt; ++t)
#pragma unroll
        for (int j = 0; j < 4; ++j) m = fmaxf(m, sc[t][j]);
    for (int x = 1; x < 16; x <<= 1) m = fmaxf(m, __shfl_xor(m, x));
    float l = 0;
    for (int t = 0; t < nt; ++t)
#pragma unroll
        for (int j = 0; j < 4; ++j) {
            float p = __expf(sc[t][j] - m);
            sc[t][j] = p;
            l += p;
        }
    for (int x = 1; x < 16; x <<= 1) l += __shfl_xor(l, x);
    float o0 = 0, o1 = 0, o2 = 0, o3 = 0;
    for (int t = 0; t < nt; ++t) {
        __syncthreads();
#pragma unroll
        for (int it = 0; it < 2; ++it) {
            int id = tid + (it << 9);
            int row = id >> 4, c4 = id & 15;
            KVs[row][c4] = *(const float4*)(V + (size_t)(b * SEQ + (t << 6) + row)
                                            * (KVHEAD * HDIM) + kv * HDIM + (c4 << 2));
        }
        Ps[qi][li +  0] = sc[t][0];
        Ps[qi][li + 16] = sc[t][1];
        Ps[qi][li + 32] = sc[t][2];
        Ps[qi][li + 48] = sc[t][3];
        __syncthreads();
#pragma unroll
        for (int j = 0; j < 64; ++j) {
            float p = Ps[qi][j];
            float4 v4 = KVs[j][li];
            o0 = fmaf(p, v4.x, o0);
            o1 = fmaf(p, v4.y, o1);
            o2 = fmaf(p, v4.z, o2);
            o3 = fmaf(p, v4.w, o3);
        }
    }
    float inv = 1.0f / l;
    *(float4*)(O + (size_t)(b * SEQ + q0 + qi) * HID + n * HDIM + (li << 2)) =
        make_float4(o0 * inv, o1 * inv, o2 * inv, o3 * inv);
}

// ---------------------------------------------------------------------------
// Group attention: MHA across the 8 channels. One wave per (s, head).
// ---------------------------------------------------------------------------
__global__ __launch_bounds__(64)
void attn_group(const float* __restrict__ Q, const float* __restrict__ K,
                const float* __restrict__ V, const float* __restrict__ gmask,
                float* __restrict__ O) {
    const int n = blockIdx.x % NHEAD;
    const int s = blockIdx.x / NHEAD;
    const int kv = n / REP;
    const int lane = threadIdx.x;
    __shared__ float Qs[8][65], Ks[8][65], Vs[8][65], Ps[64];
    for (int c = 0; c < 8; ++c) {
        Qs[c][lane] = Q[(size_t)(c * SEQ + s) * HID + n * HDIM + lane];
        Ks[c][lane] = K[(size_t)(c * SEQ + s) * (KVHEAD * HDIM) + kv * HDIM + lane];
        Vs[c][lane] = V[(size_t)(c * SEQ + s) * (KVHEAD * HDIM) + kv * HDIM + lane];
    }
    __syncthreads();
    const int qb = lane >> 3, kb = lane & 7;
    float sc = 0;
    for (int d = 0; d < 64; ++d) sc += Qs[qb][d] * Ks[kb][d];
    sc = sc * 0.125f + gmask[(size_t)s * 64 + qb * 8 + kb];
    float m = sc;
    for (int x = 1; x < 8; x <<= 1) m = fmaxf(m, __shfl_xor(m, x));
    float p = __expf(sc - m);
    float l = p;
    for (int x = 1; x < 8; x <<= 1) l += __shfl_xor(l, x);
    Ps[lane] = p / l;
    __syncthreads();
    for (int q2 = 0; q2 < 8; ++q2) {
        float o = 0;
        for (int c = 0; c < 8; ++c) o += Ps[q2 * 8 + c] * Vs[c][lane];
        O[(size_t)(q2 * SEQ + s) * HID + n * HDIM + lane] = o;
    }
}

// ---------------------------------------------------------------------------
// MoE router (fp32)
// ---------------------------------------------------------------------------
__global__ __launch_bounds__(64)
void router_kernel(const float* __restrict__ X, const float* __restrict__ GW,
                   int* __restrict__ counts, int* __restrict__ topi,
                   float* __restrict__ topw, int* __restrict__ posb) {
    const int t = blockIdx.x;
    const int lane = threadIdx.x;
    const int e = lane >> 3, c = lane & 7;
    const float4* x4 = (const float4*)(X + (size_t)t * HID + c * 96);
    const float4* g4 = (const float4*)(GW + (size_t)e * HID + c * 96);
    float p = 0;
#pragma unroll
    for (int i = 0; i < 24; ++i) {
        float4 xv = x4[i], gv = g4[i];
        p += xv.x * gv.x + xv.y * gv.y + xv.z * gv.z + xv.w * gv.w;
    }
    p += __shfl_xor(p, 1);
    p += __shfl_xor(p, 2);
    p += __shfl_xor(p, 4);
    float lg[8];
#pragma unroll
    for (int i = 0; i < 8; ++i) lg[i] = __shfl(p, i * 8);
    float m = lg[0];
#pragma unroll
    for (int i = 1; i < 8; ++i) m = fmaxf(m, lg[i]);
    float s = 0;
#pragma unroll
    for (int i = 0; i < 8; ++i) { lg[i] = expf(lg[i] - m); s += lg[i]; }
    float inv = 1.0f / s;
    int i1 = 0; float b1 = lg[0];
#pragma unroll
    for (int i = 1; i < 8; ++i) if (lg[i] > b1) { b1 = lg[i]; i1 = i; }
    int i2 = -1; float b2 = -1.0f;
#pragma unroll
    for (int i = 0; i < 8; ++i)
        if (i != i1 && lg[i] > b2) { b2 = lg[i]; i2 = i; }
    if (lane == 0) {
        topi[t * 2] = i1; topi[t * 2 + 1] = i2;
        topw[t * 2] = b1 * inv; topw[t * 2 + 1] = b2 * inv;
        posb[t * 2] = atomicAdd(&counts[i1], 1);
        posb[t * 2 + 1] = atomicAdd(&counts[i2], 1);
    }
}

__global__ void scan_kernel(const int* __restrict__ counts, int* __restrict__ offsets) {
    int acc = 0;
    for (int e = 0; e < NEXP; ++e) { offsets[e] = acc; acc += counts[e]; }
}

__global__ __launch_bounds__(256)
void fill_slots(const int* __restrict__ topi, const float* __restrict__ topw,
                const int* __restrict__ posb, const int* __restrict__ offsets,
                int* __restrict__ slot_token, float* __restrict__ slot_w,
                int* __restrict__ token_slot) {
    int t = blockIdx.x * 256 + threadIdx.x;
    if (t >= NTOK) return;
#pragma unroll
    for (int k = 0; k < TOPK; ++k) {
        int e = topi[t * 2 + k];
        int sl = offsets[e] + posb[t * 2 + k];
        slot_token[sl] = t;
        slot_w[sl] = topw[t * 2 + k];
        token_slot[t * 2 + k] = sl;
    }
}

// ---------------------------------------------------------------------------
// MoE gate+up grouped GEMM. A fp32 gathered + split hi/lo; Wg/Wu bf16
// [e][IEXP][HID]. H bf16 out. Grid (12, 32, 8).
// ---------------------------------------------------------------------------
__global__ __launch_bounds__(256)
void moe_gate_up(const float* __restrict__ X, const u16* __restrict__ Wg,
                 const u16* __restrict__ Wu,
                 const int* __restrict__ slot_token,
                 const int* __restrict__ counts,
                 const int* __restrict__ offsets, u16* __restrict__ H) {
    const int e = blockIdx.z;
    const int Ce = counts[e];
    const int m0 = blockIdx.y << 7;
    if (Ce == 0 || m0 >= Ce) return;
    const int n0 = blockIdx.x << 7;
    const int base = offsets[e];
    __shared__ __align__(16) u16 Ah[4096];
    __shared__ __align__(16) u16 Al[4096];
    __shared__ __align__(16) u16 Gs[4096];
    __shared__ __align__(16) u16 Us[4096];
    const int tid = threadIdx.x, l = tid & 63, w = tid >> 6;
    const int wm = w & 1, wn = w >> 1;
    const int sr = l >> 2, sc8 = (l & 3) << 3;
    int r0 = m0 + w * 32 + sr;
    int r1 = r0 + 16;
    int t0 = slot_token[base + min(r0, Ce - 1)];
    int t1 = slot_token[base + min(r1, Ce - 1)];
    const float* gA0 = X + (size_t)t0 * HID + sc8;
    const float* gA1 = X + (size_t)t1 * HID + sc8;
    const u16* Wge = Wg + (size_t)e * IEXP * HID;
    const u16* Wue = Wu + (size_t)e * IEXP * HID;
    const u16* gG0 = Wge + (size_t)(n0 + w * 32 + sr) * HID + sc8;
    const u16* gG1 = gG0 + 16 * HID;
    const u16* gU0 = Wue + (size_t)(n0 + w * 32 + sr) * HID + sc8;
    const u16* gU1 = gU0 + 16 * HID;
    const int aoff0 = (w * 32 + sr) * 32 + sc8, aoff1 = aoff0 + 512;
    u16* lG0 = Gs + w * 1024; u16* lG1 = lG0 + 512;
    u16* lU0 = Us + w * 1024; u16* lU1 = lU0 + 512;
    const int fr = l & 15, fc = (l >> 4) << 3;
    f32x4 accg[4][4], accu[4][4];
#pragma unroll
    for (int i = 0; i < 4; ++i)
#pragma unroll
        for (int j = 0; j < 4; ++j) {
            accg[i][j] = (f32x4){0.f, 0.f, 0.f, 0.f};
            accu[i][j] = (f32x4){0.f, 0.f, 0.f, 0.f};
        }
    for (int k0 = 0; k0 < HID; k0 += 32) {
        float4 a00 = *(const float4*)(gA0 + k0);
        float4 a01 = *(const float4*)(gA0 + k0 + 4);
        float4 a10 = *(const float4*)(gA1 + k0);
        float4 a11 = *(const float4*)(gA1 + k0 + 4);
        gload16(gG0 + k0, lG0);
        gload16(gG1 + k0, lG1);
        gload16(gU0 + k0, lU0);
        gload16(gU1 + k0, lU1);
        u16x8 h0, lo0, h1, lo1;
        cvt8(a00, a01, h0, lo0);
        cvt8(a10, a11, h1, lo1);
        *(u16x8*)(Ah + aoff0) = h0; *(u16x8*)(Al + aoff0) = lo0;
        *(u16x8*)(Ah + aoff1) = h1; *(u16x8*)(Al + aoff1) = lo1;
        __syncthreads();
        bf16x8 ah[4], al[4], gf[4], uf[4];
#pragma unroll
        for (int i = 0; i < 4; ++i) {
            ah[i] = *(const bf16x8*)(Ah + (wm * 64 + i * 16 + fr) * 32 + fc);
            al[i] = *(const bf16x8*)(Al + (wm * 64 + i * 16 + fr) * 32 + fc);
            gf[i] = *(const bf16x8*)(Gs + (wn * 64 + i * 16 + fr) * 32 + fc);
            uf[i] = *(const bf16x8*)(Us + (wn * 64 + i * 16 + fr) * 32 + fc);
        }
#pragma unroll
        for (int mf = 0; mf < 4; ++mf)
#pragma unroll
            for (int nf = 0; nf < 4; ++nf) {
                accg[mf][nf] = __builtin_amdgcn_mfma_f32_16x16x32_bf16(
                    ah[mf], gf[nf], accg[mf][nf], 0, 0, 0);
                accg[mf][nf] = __builtin_amdgcn_mfma_f32_16x16x32_bf16(
                    al[mf], gf[nf], accg[mf][nf], 0, 0, 0);
                accu[mf][nf] = __builtin_amdgcn_mfma_f32_16x16x32_bf16(
                    ah[mf], uf[nf], accu[mf][nf], 0, 0, 0);
                accu[mf][nf] = __builtin_amdgcn_mfma_f32_16x16x32_bf16(
                    al[mf], uf[nf], accu[mf][nf], 0, 0, 0);
            }
        __syncthreads();
    }
    const int er = (l >> 4) << 2, ec = l & 15;
#pragma unroll
    for (int mf = 0; mf < 4; ++mf)
#pragma unroll
        for (int i = 0; i < 4; ++i) {
            int row = m0 + wm * 64 + mf * 16 + er + i;
            if (row >= Ce) continue;
            size_t sl = (size_t)(base + row);
#pragma unroll
            for (int nf = 0; nf < 4; ++nf) {
                int col = n0 + wn * 64 + nf * 16 + ec;
                float g = accg[mf][nf][i];
                float u = accu[mf][nf][i];
                float h = g / (1.0f + __expf(-g)) * u;
                H[sl * IEXP + col] = f2bf(h);
            }
        }
}

// ---------------------------------------------------------------------------
// MoE down grouped GEMM bf16: D[slot][HID] fp32 = slot_w * (H @ Wd^T)
// Wd pre-transposed to [e][HID][IEXP]. Grid (6, 32, 8).
// ---------------------------------------------------------------------------
__global__ __launch_bounds__(256)
void moe_down_bf16(const u16* __restrict__ Hb, const u16* __restrict__ Wd,
                   const float* __restrict__ slot_w,
                   const int* __restrict__ counts,
                   const int* __restrict__ offsets, float* __restrict__ D) {
    const int e = blockIdx.z;
    const int Ce = counts[e];
    const int m0 = blockIdx.y << 7;
    if (Ce == 0 || m0 >= Ce) return;
    const int n0 = blockIdx.x << 7;
    const int base = offsets[e];
    __shared__ __align__(16) u16 As[4096];
    __shared__ __align__(16) u16 Bs[4096];
    const int tid = threadIdx.x, l = tid & 63, w = tid >> 6;
    const int wm = w & 1, wn = w >> 1;
    const int sr = l >> 2, sc = (l & 3) << 3;
    const u16* Ae = Hb + (size_t)base * IEXP;
    int r0 = min(m0 + w * 32 + sr, Ce - 1);
    int r1 = min(m0 + w * 32 + 16 + sr, Ce - 1);
    const u16* gA0 = Ae + (size_t)r0 * IEXP + sc;
    const u16* gA1 = Ae + (size_t)r1 * IEXP + sc;
    const u16* Wde = Wd + (size_t)e * HID * IEXP;
    const u16* gB0 = Wde + (size_t)(n0 + w * 32 + sr) * IEXP + sc;
    const u16* gB1 = gB0 + 16 * IEXP;
    u16* lA0 = As + w * 1024; u16* lA1 = lA0 + 512;
    u16* lB0 = Bs + w * 1024; u16* lB1 = lB0 + 512;
    const int fr = l & 15, fc = (l >> 4) << 3;
    f32x4 acc[4][4];
#pragma unroll
    for (int i = 0; i < 4; ++i)
#pragma unroll
        for (int j = 0; j < 4; ++j) acc[i][j] = (f32x4){0.f, 0.f, 0.f, 0.f};
    for (int k0 = 0; k0 < IEXP; k0 += 32) {
        gload16(gA0 + k0, lA0);
        gload16(gA1 + k0, lA1);
        gload16(gB0 + k0, lB0);
        gload16(gB1 + k0, lB1);
        __syncthreads();
        bf16x8 af[4], bfv[4];
#pragma unroll
        for (int i = 0; i < 4; ++i) {
            af[i]  = *(const bf16x8*)(As + (wm * 64 + i * 16 + fr) * 32 + fc);
            bfv[i] = *(const bf16x8*)(Bs + (wn * 64 + i * 16 + fr) * 32 + fc);
        }
#pragma unroll
        for (int mf = 0; mf < 4; ++mf)
#pragma unroll
            for (int nf = 0; nf < 4; ++nf)
                acc[mf][nf] = __builtin_amdgcn_mfma_f32_16x16x32_bf16(
                    af[mf], bfv[nf], acc[mf][nf], 0, 0, 0);
        __syncthreads();
    }
    const int er = (l >> 4) << 2, ec = l & 15;
#pragma unroll
    for (int mf = 0; mf < 4; ++mf)
#pragma unroll
        for (int i = 0; i < 4; ++i) {
            int row = m0 + wm * 64 + mf * 16 + er + i;
            if (row >= Ce) continue;
            size_t sl = (size_t)(base + row);
            float sw = slot_w[sl];
#pragma unroll
            for (int nf = 0; nf < 4; ++nf) {
                int col = n0 + wn * 64 + nf * 16 + ec;
                D[sl * HID + col] = acc[mf][nf][i] * sw;
            }
        }
}

__global__ __launch_bounds__(256)
void moe_add(float* __restrict__ out, const float* __restrict__ D,
             const int* __restrict__ token_slot) {
    const int t = blockIdx.y;
    const int h = blockIdx.x * 256 + threadIdx.x;
    int s0 = token_slot[t * 2], s1 = token_slot[t * 2 + 1];
    out[(size_t)t * HID + h] += D[(size_t)s0 * HID + h] + D[(size_t)s1 * HID + h];
}

// ---------------------------------------------------------------------------
extern "C" void kernel_launch(void* const* d_in, const int* in_sizes, int n_in,
                              void* d_out, int out_size, void* d_ws, size_t ws_size,
                              hipStream_t stream) {
    const float* hidden = (const float*)d_in[0];
    const float* amask  = (const float*)d_in[1];
    const float* gmask  = (const float*)d_in[2];
    const int*   posids = (const int*)d_in[3];
    const float* ln1 = (const float*)d_in[4];
    const float* ln2 = (const float*)d_in[5];
    const float* ln3 = (const float*)d_in[6];
    const float* sqw = (const float*)d_in[7];  const float* sqb = (const float*)d_in[8];
    const float* skw = (const float*)d_in[9];  const float* skb = (const float*)d_in[10];
    const float* svw = (const float*)d_in[11]; const float* svb = (const float*)d_in[12];
    const float* sow = (const float*)d_in[13];
    const float* gqw = (const float*)d_in[14]; const float* gqb = (const float*)d_in[15];
    const float* gkw = (const float*)d_in[16]; const float* gkb = (const float*)d_in[17];
    const float* gvw = (const float*)d_in[18]; const float* gvb = (const float*)d_in[19];
    const float* gow = (const float*)d_in[20];
    const float* gatew = (const float*)d_in[21];
    const float* wg = (const float*)d_in[22];
    const float* wu = (const float*)d_in[23];
    const float* wd = (const float*)d_in[24];
    float* out = (float*)d_out;

    // ---- workspace carve (byte offsets), ~109.3 MB total ----
    char* base = (char*)d_ws;
    float* xb    = (float*)(base + 0);          // 12,582,912 (live thru MoE gather)
    float* qb    = (float*)(base + 12582912);   // 12,582,912
    float* kbuf  = (float*)(base + 25165824);   //  4,194,304
    float* vbuf  = (float*)(base + 29360128);   //  4,194,304
    float* ab    = (float*)(base + 33554432);   // 12,582,912 -> 46,137,344
    u16*   wgt   = (u16*)  (base + 52428800);   // 18,874,368 -> 71,303,168
    u16*   wut   = (u16*)  (base + 71303168);   // 18,874,368 -> 90,177,536
    u16*   wdt   = (u16*)  (base + 90177536);   // 18,874,368 -> 109,051,904
    float* slotw = (float*)(base + 109051904);
    float* topw  = (float*)(base + 109084672);
    int* counts  = (int*)  (base + 109117440);
    int* offsets = (int*)  (base + 109117696);
    int* topi    = (int*)  (base + 109117952);
    int* posb    = (int*)  (base + 109150720);
    int* slot_token = (int*)(base + 109183488);
    int* token_slot = (int*)(base + 109216256);
    // MoE-phase overlays (qb/kbuf/vbuf/ab + wgt-head dead when used):
    u16*   Hbuf  = (u16*)  (base + 12582912);   // 25,165,824 -> 37,748,736
    float* Dbuf  = (float*)(base + 37748736);   // 25,165,824 -> 62,914,560

    // ---- MoE weight transpose+convert (fp32 inputs every call) ----
    transpose_cvt<<<dim3(48, 24, 8), dim3(32, 8), 0, stream>>>(wg, wgt, HID, IEXP);
    transpose_cvt<<<dim3(48, 24, 8), dim3(32, 8), 0, stream>>>(wu, wut, HID, IEXP);
    transpose_cvt<<<dim3(24, 48, 8), dim3(32, 8), 0, stream>>>(wd, wdt, IEXP, HID);

    // ---- self attention (fp32 path: router-flip safe) ----
    rmsnorm_kernel<<<NTOK, 256, 0, stream>>>(hidden, ln1, xb);
    qkv_f32<<<dim3(10, 32), 256, 0, stream>>>(xb, sqw, skw, svw, sqb, skb, svb,
                                              qb, kbuf, vbuf);
    rope_kernel<<<NTOK, 256, 0, stream>>>(qb, kbuf, posids);
    attn_self<<<dim3(SEQ / 32, NHEAD, BATCH), 512, 0, stream>>>(qb, kbuf, vbuf, amask, ab);
    gemm_f32<<<dim3(6, 32), 256, 0, stream>>>(ab, sow, hidden, out, NTOK, HID, HID);

    // ---- group attention (fp32 path) ----
    rmsnorm_kernel<<<NTOK, 256, 0, stream>>>(out, ln2, xb);
    qkv_f32<<<dim3(10, 32), 256, 0, stream>>>(xb, gqw, gkw, gvw, gqb, gkb, gvb,
                                              qb, kbuf, vbuf);
    attn_group<<<SEQ * NHEAD, 64, 0, stream>>>(qb, kbuf, vbuf, gmask, ab);
    gemm_f32<<<dim3(6, 32), 256, 0, stream>>>(ab, gow, out, out, NTOK, HID, HID);

    // ---- MoE (bf16 MFMA: post-router, flip-free) ----
    rmsnorm_kernel<<<NTOK, 256, 0, stream>>>(out, ln3, xb);
    hipMemsetAsync(counts, 0, 8 * sizeof(int), stream);
    router_kernel<<<NTOK, 64, 0, stream>>>(xb, gatew, counts, topi, topw, posb);
    scan_kernel<<<1, 1, 0, stream>>>(counts, offsets);
    fill_slots<<<16, 256, 0, stream>>>(topi, topw, posb, offsets,
                                       slot_token, slotw, token_slot);
    moe_gate_up<<<dim3(12, 32, 8), 256, 0, stream>>>(
        xb, wgt, wut, slot_token, counts, offsets, Hbuf);
    moe_down_bf16<<<dim3(6, 32, 8), 256, 0, stream>>>(
        Hbuf, wdt, slotw, counts, offsets, Dbuf);
    moe_add<<<dim3(3, NTOK), 256, 0, stream>>>(out, Dbuf, token_slot);
}

// Round 6
// 676.754 us; speedup vs baseline: 2.4188x; 1.6247x over previous
//
#include <hip/hip_runtime.h>
#include <math.h>

// Problem constants
#define BATCH 8
#define SEQ 512
#define HID 768
#define NHEAD 12
#define KVHEAD 4
#define HDIM 64
#define NEXP 8
#define TOPK 2
#define IEXP 1536
#define NTOK (BATCH * SEQ)     // 4096
#define NSLOT (NTOK * TOPK)    // 8192
#define REP (NHEAD / KVHEAD)   // 3

typedef unsigned short u16;
typedef float f32x4 __attribute__((ext_vector_type(4)));
typedef __bf16 bf16x8 __attribute__((ext_vector_type(8)));
typedef unsigned short u16x8 __attribute__((ext_vector_type(8)));

__device__ __forceinline__ u16 f2bf(float f) {
    unsigned u = __float_as_uint(f);
    u += 0x7fffu + ((u >> 16) & 1u);   // RNE
    return (u16)(u >> 16);
}
__device__ __forceinline__ float bf2f(u16 h) {
    return __uint_as_float(((unsigned)h) << 16);
}

__device__ __forceinline__ void gload16(const void* g, void* l) {
    __builtin_amdgcn_global_load_lds(
        (const __attribute__((address_space(1))) void*)g,
        (__attribute__((address_space(3))) void*)l, 16, 0, 0);
}

// split 8 fp32 -> hi/lo bf16
__device__ __forceinline__ void cvt8(float4 a, float4 b, u16x8& hi, u16x8& lo) {
    float x[8] = {a.x, a.y, a.z, a.w, b.x, b.y, b.z, b.w};
#pragma unroll
    for (int i = 0; i < 8; ++i) {
        u16 h = f2bf(x[i]);
        hi[i] = h;
        lo[i] = f2bf(x[i] - bf2f(h));
    }
}

// swizzled element offset in a row-major [R][64] bf16 LDS tile (stride 128B):
// XOR the 16B-chunk index with (row&7) -> 2-way max bank aliasing (free).
#define SW(row, col) (((row) << 6) + ((col) ^ (((row) & 7) << 3)))

// ---------------------------------------------------------------------------
// fp32 -> bf16 hi/lo split convert (weights)
// ---------------------------------------------------------------------------
__global__ __launch_bounds__(256)
void cvt_split(const float* __restrict__ x, u16* __restrict__ yh,
               u16* __restrict__ yl, int n) {
    int i = (blockIdx.x * 256 + threadIdx.x) * 4;
    if (i >= n) return;
    float4 v = *(const float4*)(x + i);
    float a[4] = {v.x, v.y, v.z, v.w};
    ushort4 h, lo;
    u16 t;
    t = f2bf(a[0]); h.x = t; lo.x = f2bf(a[0] - bf2f(t));
    t = f2bf(a[1]); h.y = t; lo.y = f2bf(a[1] - bf2f(t));
    t = f2bf(a[2]); h.z = t; lo.z = f2bf(a[2] - bf2f(t));
    t = f2bf(a[3]); h.w = t; lo.w = f2bf(a[3] - bf2f(t));
    *(ushort4*)(yh + i) = h;
    *(ushort4*)(yl + i) = lo;
}

// ---------------------------------------------------------------------------
// per-expert transpose + convert: src[e][R][C] fp32 -> dst[e][C][R] bf16
// ---------------------------------------------------------------------------
__global__ __launch_bounds__(256)
void transpose_cvt(const float* __restrict__ src, u16* __restrict__ dst,
                   int R, int C) {
    const int e = blockIdx.z;
    src += (size_t)e * R * C;
    dst += (size_t)e * R * C;
    __shared__ float t[32][33];
    const int c0 = blockIdx.x << 5, r0 = blockIdx.y << 5;
    const int tx = threadIdx.x, ty = threadIdx.y;
#pragma unroll
    for (int i = 0; i < 4; ++i)
        t[ty * 4 + i][tx] = src[(size_t)(r0 + ty * 4 + i) * C + c0 + tx];
    __syncthreads();
#pragma unroll
    for (int i = 0; i < 4; ++i)
        dst[(size_t)(c0 + ty * 4 + i) * R + r0 + tx] = f2bf(t[tx][ty * 4 + i]);
}

// ---------------------------------------------------------------------------
// RMSNorm: one block per token (fp32 out)
// ---------------------------------------------------------------------------
__global__ __launch_bounds__(256)
void rmsnorm_kernel(const float* __restrict__ X, const float* __restrict__ W,
                    float* __restrict__ Y) {
    const int t = blockIdx.x;
    const int tid = threadIdx.x;
    const float* x = X + (size_t)t * HID;
    float x0 = x[tid], x1 = x[tid + 256], x2 = x[tid + 512];
    float ss = x0 * x0 + x1 * x1 + x2 * x2;
    for (int m = 1; m < 64; m <<= 1) ss += __shfl_xor(ss, m);
    __shared__ float red[4];
    if ((tid & 63) == 0) red[tid >> 6] = ss;
    __syncthreads();
    float tot = red[0] + red[1] + red[2] + red[3];
    float inv = rsqrtf(tot * (1.0f / HID) + 1e-6f);
    float* y = Y + (size_t)t * HID;
    y[tid]       = x0 * inv * W[tid];
    y[tid + 256] = x1 * inv * W[tid + 256];
    y[tid + 512] = x2 * inv * W[tid + 512];
}

// ---------------------------------------------------------------------------
// Split-precision MFMA NT GEMM for QKV. A fp32 (hi/lo in-kernel),
// Wh/Wl bf16 [1280][768]. 128x128 tile, BK=32. Grid (10, 32).
// acc = ah*bh + al*bh + ah*bl  (ll term ~2^-18, dropped)
// ---------------------------------------------------------------------------
__global__ __launch_bounds__(256)
void qkv_split(const float* __restrict__ X, const u16* __restrict__ Wh,
               const u16* __restrict__ Wl,
               const float* __restrict__ bq, const float* __restrict__ bk,
               const float* __restrict__ bv,
               float* __restrict__ Qo, float* __restrict__ Ko,
               float* __restrict__ Vo) {
    __shared__ __align__(16) u16 Ah[4096], Al[4096], Bh[4096], Bl[4096];
    const int tid = threadIdx.x, l = tid & 63, w = tid >> 6;
    const int wm = w & 1, wn = w >> 1;
    const int m0 = blockIdx.y << 7, n0 = blockIdx.x << 7;
    const int sr = l >> 2, sc8 = (l & 3) << 3;
    const float* gA0 = X + (size_t)(m0 + w * 32 + sr) * HID + sc8;
    const float* gA1 = gA0 + 16 * HID;
    const u16* gBh0 = Wh + (size_t)(n0 + w * 32 + sr) * HID + sc8;
    const u16* gBh1 = gBh0 + 16 * HID;
    const u16* gBl0 = Wl + (size_t)(n0 + w * 32 + sr) * HID + sc8;
    const u16* gBl1 = gBl0 + 16 * HID;
    const int aoff0 = (w * 32 + sr) * 32 + sc8, aoff1 = aoff0 + 512;
    u16* lBh0 = Bh + w * 1024; u16* lBh1 = lBh0 + 512;
    u16* lBl0 = Bl + w * 1024; u16* lBl1 = lBl0 + 512;
    const int fr = l & 15, fc = (l >> 4) << 3;
    f32x4 acc[4][4];
#pragma unroll
    for (int i = 0; i < 4; ++i)
#pragma unroll
        for (int j = 0; j < 4; ++j) acc[i][j] = (f32x4){0.f, 0.f, 0.f, 0.f};
    for (int k0 = 0; k0 < HID; k0 += 32) {
        float4 a00 = *(const float4*)(gA0 + k0);
        float4 a01 = *(const float4*)(gA0 + k0 + 4);
        float4 a10 = *(const float4*)(gA1 + k0);
        float4 a11 = *(const float4*)(gA1 + k0 + 4);
        gload16(gBh0 + k0, lBh0);
        gload16(gBh1 + k0, lBh1);
        gload16(gBl0 + k0, lBl0);
        gload16(gBl1 + k0, lBl1);
        u16x8 h0, l0v, h1, l1v;
        cvt8(a00, a01, h0, l0v);
        cvt8(a10, a11, h1, l1v);
        *(u16x8*)(Ah + aoff0) = h0; *(u16x8*)(Al + aoff0) = l0v;
        *(u16x8*)(Ah + aoff1) = h1; *(u16x8*)(Al + aoff1) = l1v;
        __syncthreads();
        bf16x8 ah[4], al[4], bh[4], bl[4];
#pragma unroll
        for (int i = 0; i < 4; ++i) {
            ah[i] = *(const bf16x8*)(Ah + (wm * 64 + i * 16 + fr) * 32 + fc);
            al[i] = *(const bf16x8*)(Al + (wm * 64 + i * 16 + fr) * 32 + fc);
            bh[i] = *(const bf16x8*)(Bh + (wn * 64 + i * 16 + fr) * 32 + fc);
            bl[i] = *(const bf16x8*)(Bl + (wn * 64 + i * 16 + fr) * 32 + fc);
        }
#pragma unroll
        for (int mf = 0; mf < 4; ++mf)
#pragma unroll
            for (int nf = 0; nf < 4; ++nf) {
                acc[mf][nf] = __builtin_amdgcn_mfma_f32_16x16x32_bf16(
                    ah[mf], bh[nf], acc[mf][nf], 0, 0, 0);
                acc[mf][nf] = __builtin_amdgcn_mfma_f32_16x16x32_bf16(
                    al[mf], bh[nf], acc[mf][nf], 0, 0, 0);
                acc[mf][nf] = __builtin_amdgcn_mfma_f32_16x16x32_bf16(
                    ah[mf], bl[nf], acc[mf][nf], 0, 0, 0);
            }
        __syncthreads();
    }
    float* outp; const float* bp; int ldc, nl;
    if (n0 < 768)       { outp = Qo; bp = bq; ldc = 768; nl = n0; }
    else if (n0 < 1024) { outp = Ko; bp = bk; ldc = 256; nl = n0 - 768; }
    else                { outp = Vo; bp = bv; ldc = 256; nl = n0 - 1024; }
    const int er = (l >> 4) << 2, ec = l & 15;
#pragma unroll
    for (int mf = 0; mf < 4; ++mf)
#pragma unroll
        for (int i = 0; i < 4; ++i) {
            int row = m0 + wm * 64 + mf * 16 + er + i;
#pragma unroll
            for (int nf = 0; nf < 4; ++nf) {
                int col = nl + wn * 64 + nf * 16 + ec;
                outp[(size_t)row * ldc + col] = acc[mf][nf][i] + bp[col];
            }
        }
}

// ---------------------------------------------------------------------------
// Split-precision MFMA NT GEMM with residual: C = A@W^T + resid.
// ---------------------------------------------------------------------------
__global__ __launch_bounds__(256)
void oproj_split(const float* __restrict__ A, const u16* __restrict__ Wh,
                 const u16* __restrict__ Wl, const float* __restrict__ resid,
                 float* __restrict__ C, int M, int N, int K) {
    __shared__ __align__(16) u16 Ah[4096], Al[4096], Bh[4096], Bl[4096];
    const int tid = threadIdx.x, l = tid & 63, w = tid >> 6;
    const int wm = w & 1, wn = w >> 1;
    const int m0 = blockIdx.y << 7, n0 = blockIdx.x << 7;
    const int sr = l >> 2, sc8 = (l & 3) << 3;
    const float* gA0 = A + (size_t)(m0 + w * 32 + sr) * K + sc8;
    const float* gA1 = gA0 + (size_t)16 * K;
    const u16* gBh0 = Wh + (size_t)(n0 + w * 32 + sr) * K + sc8;
    const u16* gBh1 = gBh0 + (size_t)16 * K;
    const u16* gBl0 = Wl + (size_t)(n0 + w * 32 + sr) * K + sc8;
    const u16* gBl1 = gBl0 + (size_t)16 * K;
    const int aoff0 = (w * 32 + sr) * 32 + sc8, aoff1 = aoff0 + 512;
    u16* lBh0 = Bh + w * 1024; u16* lBh1 = lBh0 + 512;
    u16* lBl0 = Bl + w * 1024; u16* lBl1 = lBl0 + 512;
    const int fr = l & 15, fc = (l >> 4) << 3;
    f32x4 acc[4][4];
#pragma unroll
    for (int i = 0; i < 4; ++i)
#pragma unroll
        for (int j = 0; j < 4; ++j) acc[i][j] = (f32x4){0.f, 0.f, 0.f, 0.f};
    for (int k0 = 0; k0 < K; k0 += 32) {
        float4 a00 = *(const float4*)(gA0 + k0);
        float4 a01 = *(const float4*)(gA0 + k0 + 4);
        float4 a10 = *(const float4*)(gA1 + k0);
        float4 a11 = *(const float4*)(gA1 + k0 + 4);
        gload16(gBh0 + k0, lBh0);
        gload16(gBh1 + k0, lBh1);
        gload16(gBl0 + k0, lBl0);
        gload16(gBl1 + k0, lBl1);
        u16x8 h0, l0v, h1, l1v;
        cvt8(a00, a01, h0, l0v);
        cvt8(a10, a11, h1, l1v);
        *(u16x8*)(Ah + aoff0) = h0; *(u16x8*)(Al + aoff0) = l0v;
        *(u16x8*)(Ah + aoff1) = h1; *(u16x8*)(Al + aoff1) = l1v;
        __syncthreads();
        bf16x8 ah[4], al[4], bh[4], bl[4];
#pragma unroll
        for (int i = 0; i < 4; ++i) {
            ah[i] = *(const bf16x8*)(Ah + (wm * 64 + i * 16 + fr) * 32 + fc);
            al[i] = *(const bf16x8*)(Al + (wm * 64 + i * 16 + fr) * 32 + fc);
            bh[i] = *(const bf16x8*)(Bh + (wn * 64 + i * 16 + fr) * 32 + fc);
            bl[i] = *(const bf16x8*)(Bl + (wn * 64 + i * 16 + fr) * 32 + fc);
        }
#pragma unroll
        for (int mf = 0; mf < 4; ++mf)
#pragma unroll
            for (int nf = 0; nf < 4; ++nf) {
                acc[mf][nf] = __builtin_amdgcn_mfma_f32_16x16x32_bf16(
                    ah[mf], bh[nf], acc[mf][nf], 0, 0, 0);
                acc[mf][nf] = __builtin_amdgcn_mfma_f32_16x16x32_bf16(
                    al[mf], bh[nf], acc[mf][nf], 0, 0, 0);
                acc[mf][nf] = __builtin_amdgcn_mfma_f32_16x16x32_bf16(
                    ah[mf], bl[nf], acc[mf][nf], 0, 0, 0);
            }
        __syncthreads();
    }
    const int er = (l >> 4) << 2, ec = l & 15;
#pragma unroll
    for (int mf = 0; mf < 4; ++mf)
#pragma unroll
        for (int i = 0; i < 4; ++i) {
            int row = m0 + wm * 64 + mf * 16 + er + i;
#pragma unroll
            for (int nf = 0; nf < 4; ++nf) {
                int col = n0 + wn * 64 + nf * 16 + ec;
                C[(size_t)row * N + col] =
                    acc[mf][nf][i] + resid[(size_t)row * N + col];
            }
        }
}

// ---------------------------------------------------------------------------
// RoPE in-place on q (12 heads) and k (4 heads) per token
// ---------------------------------------------------------------------------
__global__ __launch_bounds__(256)
void rope_kernel(float* __restrict__ Q, float* __restrict__ Kb,
                 const int* __restrict__ pos_ids) {
    const int t = blockIdx.x;
    const float pos = (float)pos_ids[t];
    const int tid = threadIdx.x;
#pragma unroll
    for (int it = 0; it < 2; ++it) {
        int p = tid + (it << 8);
        int head = p >> 5, i = p & 31;
        float invf = expf(-(float)i * 0.28782313662425572f); // ln(1e4)/32
        float ang = pos * invf;
        float c = cosf(ang), sn = sinf(ang);
        float* base = (head < NHEAD)
            ? (Q + (size_t)t * HID + head * HDIM)
            : (Kb + (size_t)t * (KVHEAD * HDIM) + (head - NHEAD) * HDIM);
        float x1 = base[i], x2 = base[i + 32];
        base[i]      = x1 * c - x2 * sn;
        base[i + 32] = x2 * c + x1 * sn;
    }
}

// ---------------------------------------------------------------------------
// Self attention (causal GQA) via split-precision MFMA, online softmax.
// Block: 256 thr (4 waves) = 32 queries. Tiles of 64 keys.
// Wave w: q-frag = w&1 (16 q), k/d-frag pair = (w>>1)*2 + {0,1}.
// S = 6 MFMA/frag (hh+lh+hl over two 32-d chunks); PV = 3 MFMA per (df,kc).
// LDS tiles XOR-swizzled (SW) -> 2-way max bank aliasing.
// ---------------------------------------------------------------------------
__global__ __launch_bounds__(256)
void attn_self_mfma(const float* __restrict__ Q, const float* __restrict__ K,
                    const float* __restrict__ V, float* __restrict__ O) {
    const int qt = blockIdx.x, n = blockIdx.y, b = blockIdx.z;
    const int kv = n / REP;
    const int tid = threadIdx.x, l = tid & 63, w = tid >> 6;
    const int q0 = qt << 5;
    __shared__ __align__(16) u16 Qh[2048], Ql[2048];    // [32][64]
    __shared__ __align__(16) u16 Kh[4096], Kl[4096];    // [64][64]
    __shared__ __align__(16) u16 Vh[4096], Vl[4096];    // transposed [d][key]
    __shared__ float Ps[32][68];
    __shared__ float scal[32];

    // ---- stage Q (hi/lo, swizzled) ----
    {
        int row = tid >> 3, cg = (tid & 7) << 3;
        const float* qg = Q + (size_t)(b * SEQ + q0 + row) * HID + n * HDIM + cg;
        float4 v0 = *(const float4*)qg;
        float4 v1 = *(const float4*)(qg + 4);
        u16x8 h, lo;
        cvt8(v0, v1, h, lo);
        *(u16x8*)(Qh + SW(row, cg)) = h;
        *(u16x8*)(Ql + SW(row, cg)) = lo;
    }
    __syncthreads();

    const int fr = l & 15, fcg = (l >> 4) << 3;
    const int qf16 = (w & 1) << 4;
    const int fp2 = (w >> 1) << 1;      // frag pair base (k or d)
    // preload Q fragments (d chunks 0,1)
    bf16x8 qfh[2], qfl[2];
#pragma unroll
    for (int dc = 0; dc < 2; ++dc) {
        int off = SW(qf16 + fr, dc * 32 + fcg);
        qfh[dc] = *(const bf16x8*)(Qh + off);
        qfl[dc] = *(const bf16x8*)(Ql + off);
    }

    f32x4 o[2];
    o[0] = (f32x4){0.f, 0.f, 0.f, 0.f};
    o[1] = (f32x4){0.f, 0.f, 0.f, 0.f};
    float m_run = -3.4e38f, l_run = 0.f;
    const int sq = tid >> 3;             // softmax: this thread's query
    const int skb = (tid & 7) << 3;      // and 8-key chunk
    const float scale = 0.125f;
    const int nt = (qt >> 1) + 1;

    for (int t = 0; t < nt; ++t) {
        __syncthreads();   // prior PV / frag reads done
        // ---- stage K tile (hi/lo, swizzled) ----
        {
            int row = tid >> 2, cg = (tid & 3) << 4;
            const float* kg = K + (size_t)(b * SEQ + (t << 6) + row)
                              * (KVHEAD * HDIM) + kv * HDIM + cg;
            float4 k0 = *(const float4*)kg;
            float4 k1 = *(const float4*)(kg + 4);
            float4 k2 = *(const float4*)(kg + 8);
            float4 k3 = *(const float4*)(kg + 12);
            u16x8 h0, l0v, h1, l1v;
            cvt8(k0, k1, h0, l0v);
            cvt8(k2, k3, h1, l1v);
            *(u16x8*)(Kh + SW(row, cg)) = h0;
            *(u16x8*)(Kh + SW(row, cg + 8)) = h1;
            *(u16x8*)(Kl + SW(row, cg)) = l0v;
            *(u16x8*)(Kl + SW(row, cg + 8)) = l1v;
        }
        // ---- stage V tile transposed [d][key] (hi/lo, swizzled) ----
        {
            int kp = (tid & 31) << 1, dc = (tid >> 5) << 3;
            const float* vg0 = V + (size_t)(b * SEQ + (t << 6) + kp)
                               * (KVHEAD * HDIM) + kv * HDIM + dc;
            const float* vg1 = vg0 + KVHEAD * HDIM;
            float4 a0 = *(const float4*)vg0;
            float4 a1 = *(const float4*)(vg0 + 4);
            float4 b0 = *(const float4*)vg1;
            float4 b1 = *(const float4*)(vg1 + 4);
            float va[8] = {a0.x, a0.y, a0.z, a0.w, a1.x, a1.y, a1.z, a1.w};
            float vb[8] = {b0.x, b0.y, b0.z, b0.w, b1.x, b1.y, b1.z, b1.w};
#pragma unroll
            for (int j = 0; j < 8; ++j) {
                u16 h0 = f2bf(va[j]);
                u16 h1 = f2bf(vb[j]);
                u16 p0 = f2bf(va[j] - bf2f(h0));
                u16 p1 = f2bf(vb[j] - bf2f(h1));
                int off = SW(dc + j, kp);
                *(unsigned*)(Vh + off) = (unsigned)h0 | ((unsigned)h1 << 16);
                *(unsigned*)(Vl + off) = (unsigned)p0 | ((unsigned)p1 << 16);
            }
        }
        __syncthreads();
        // ---- S = Q K^T (split MFMA), write masked+scaled to Ps ----
#pragma unroll
        for (int kk = 0; kk < 2; ++kk) {
            int kf = fp2 + kk;
            bf16x8 kh[2], klv[2];
#pragma unroll
            for (int dc = 0; dc < 2; ++dc) {
                int off = SW(kf * 16 + fr, dc * 32 + fcg);
                kh[dc]  = *(const bf16x8*)(Kh + off);
                klv[dc] = *(const bf16x8*)(Kl + off);
            }
            f32x4 s = (f32x4){0.f, 0.f, 0.f, 0.f};
            s = __builtin_amdgcn_mfma_f32_16x16x32_bf16(qfh[0], kh[0], s, 0, 0, 0);
            s = __builtin_amdgcn_mfma_f32_16x16x32_bf16(qfh[1], kh[1], s, 0, 0, 0);
            s = __builtin_amdgcn_mfma_f32_16x16x32_bf16(qfl[0], kh[0], s, 0, 0, 0);
            s = __builtin_amdgcn_mfma_f32_16x16x32_bf16(qfl[1], kh[1], s, 0, 0, 0);
            s = __builtin_amdgcn_mfma_f32_16x16x32_bf16(qfh[0], klv[0], s, 0, 0, 0);
            s = __builtin_amdgcn_mfma_f32_16x16x32_bf16(qfh[1], klv[1], s, 0, 0, 0);
            int col = kf * 16 + fr;
            int key = (t << 6) + col;
#pragma unroll
            for (int r = 0; r < 4; ++r) {
                int qrow = qf16 + ((l >> 4) << 2) + r;
                Ps[qrow][col] = (key <= q0 + qrow) ? s[r] * scale : -1e9f;
            }
        }
        __syncthreads();
        // ---- online softmax update (8 threads per query) ----
        {
            float4 s0 = *(const float4*)&Ps[sq][skb];
            float4 s1 = *(const float4*)&Ps[sq][skb + 4];
            float sv[8] = {s0.x, s0.y, s0.z, s0.w, s1.x, s1.y, s1.z, s1.w};
            float mx = sv[0];
#pragma unroll
            for (int j = 1; j < 8; ++j) mx = fmaxf(mx, sv[j]);
            for (int x = 1; x < 8; x <<= 1) mx = fmaxf(mx, __shfl_xor(mx, x));
            float mnew = fmaxf(m_run, mx);
            float corr = __expf(m_run - mnew);
            float lsum = 0.f;
#pragma unroll
            for (int j = 0; j < 8; ++j) {
                sv[j] = __expf(sv[j] - mnew);
                lsum += sv[j];
            }
            for (int x = 1; x < 8; x <<= 1) lsum += __shfl_xor(lsum, x);
            l_run = l_run * corr + lsum;
            m_run = mnew;
            *(float4*)&Ps[sq][skb]     = make_float4(sv[0], sv[1], sv[2], sv[3]);
            *(float4*)&Ps[sq][skb + 4] = make_float4(sv[4], sv[5], sv[6], sv[7]);
            if ((tid & 7) == 0) scal[sq] = corr;
        }
        __syncthreads();
        // ---- rescale O, then O += P V (split MFMA) ----
        {
            float4 c4 = *(const float4*)&scal[qf16 + ((l >> 4) << 2)];
            float cr[4] = {c4.x, c4.y, c4.z, c4.w};
#pragma unroll
            for (int dfi = 0; dfi < 2; ++dfi)
#pragma unroll
                for (int r = 0; r < 4; ++r) o[dfi][r] *= cr[r];
            bf16x8 ph[2], pl[2];
#pragma unroll
            for (int kc = 0; kc < 2; ++kc) {
                float4 p0 = *(const float4*)&Ps[qf16 + fr][kc * 32 + fcg];
                float4 p1 = *(const float4*)&Ps[qf16 + fr][kc * 32 + fcg + 4];
                u16x8 hh, ll;
                cvt8(p0, p1, hh, ll);
                ph[kc] = *(bf16x8*)&hh;
                pl[kc] = *(bf16x8*)&ll;
            }
#pragma unroll
            for (int dfi = 0; dfi < 2; ++dfi) {
                int df = fp2 + dfi;
#pragma unroll
                for (int kc = 0; kc < 2; ++kc) {
                    int off = SW(df * 16 + fr, kc * 32 + fcg);
                    bf16x8 vh = *(const bf16x8*)(Vh + off);
                    bf16x8 vl = *(const bf16x8*)(Vl + off);
                    o[dfi] = __builtin_amdgcn_mfma_f32_16x16x32_bf16(
                        ph[kc], vh, o[dfi], 0, 0, 0);
                    o[dfi] = __builtin_amdgcn_mfma_f32_16x16x32_bf16(
                        pl[kc], vh, o[dfi], 0, 0, 0);
                    o[dfi] = __builtin_amdgcn_mfma_f32_16x16x32_bf16(
                        ph[kc], vl, o[dfi], 0, 0, 0);
                }
            }
        }
    }
    __syncthreads();
    if ((tid & 7) == 0) scal[sq] = 1.0f / l_run;
    __syncthreads();
    {
        int qrb = qf16 + ((l >> 4) << 2);
        float4 li4 = *(const float4*)&scal[qrb];
        float li[4] = {li4.x, li4.y, li4.z, li4.w};
#pragma unroll
        for (int dfi = 0; dfi < 2; ++dfi) {
            int df = fp2 + dfi;
            int col = n * HDIM + df * 16 + fr;
#pragma unroll
            for (int r = 0; r < 4; ++r) {
                int row = q0 + qrb + r;
                O[(size_t)(b * SEQ + row) * HID + col] = o[dfi][r] * li[r];
            }
        }
    }
}

// ---------------------------------------------------------------------------
// Group attention: MHA across the 8 channels. One wave per (s, head).
// ---------------------------------------------------------------------------
__global__ __launch_bounds__(64)
void attn_group(const float* __restrict__ Q, const float* __restrict__ K,
                const float* __restrict__ V, const float* __restrict__ gmask,
                float* __restrict__ O) {
    const int n = blockIdx.x % NHEAD;
    const int s = blockIdx.x / NHEAD;
    const int kv = n / REP;
    const int lane = threadIdx.x;
    __shared__ float Qs[8][65], Ks[8][65], Vs[8][65], Ps[64];
    for (int c = 0; c < 8; ++c) {
        Qs[c][lane] = Q[(size_t)(c * SEQ + s) * HID + n * HDIM + lane];
        Ks[c][lane] = K[(size_t)(c * SEQ + s) * (KVHEAD * HDIM) + kv * HDIM + lane];
        Vs[c][lane] = V[(size_t)(c * SEQ + s) * (KVHEAD * HDIM) + kv * HDIM + lane];
    }
    __syncthreads();
    const int qb = lane >> 3, kb = lane & 7;
    float sc = 0;
    for (int d = 0; d < 64; ++d) sc += Qs[qb][d] * Ks[kb][d];
    sc = sc * 0.125f + gmask[(size_t)s * 64 + qb * 8 + kb];
    float m = sc;
    for (int x = 1; x < 8; x <<= 1) m = fmaxf(m, __shfl_xor(m, x));
    float p = __expf(sc - m);
    float l = p;
    for (int x = 1; x < 8; x <<= 1) l += __shfl_xor(l, x);
    Ps[lane] = p / l;
    __syncthreads();
    for (int q2 = 0; q2 < 8; ++q2) {
        float o = 0;
        for (int c = 0; c < 8; ++c) o += Ps[q2 * 8 + c] * Vs[c][lane];
        O[(size_t)(q2 * SEQ + s) * HID + n * HDIM + lane] = o;
    }
}

// ---------------------------------------------------------------------------
// MoE router (fp32)
// ---------------------------------------------------------------------------
__global__ __launch_bounds__(64)
void router_kernel(const float* __restrict__ X, const float* __restrict__ GW,
                   int* __restrict__ counts, int* __restrict__ topi,
                   float* __restrict__ topw, int* __restrict__ posb) {
    const int t = blockIdx.x;
    const int lane = threadIdx.x;
    const int e = lane >> 3, c = lane & 7;
    const float4* x4 = (const float4*)(X + (size_t)t * HID + c * 96);
    const float4* g4 = (const float4*)(GW + (size_t)e * HID + c * 96);
    float p = 0;
#pragma unroll
    for (int i = 0; i < 24; ++i) {
        float4 xv = x4[i], gv = g4[i];
        p += xv.x * gv.x + xv.y * gv.y + xv.z * gv.z + xv.w * gv.w;
    }
    p += __shfl_xor(p, 1);
    p += __shfl_xor(p, 2);
    p += __shfl_xor(p, 4);
    float lg[8];
#pragma unroll
    for (int i = 0; i < 8; ++i) lg[i] = __shfl(p, i * 8);
    float m = lg[0];
#pragma unroll
    for (int i = 1; i < 8; ++i) m = fmaxf(m, lg[i]);
    float s = 0;
#pragma unroll
    for (int i = 0; i < 8; ++i) { lg[i] = expf(lg[i] - m); s += lg[i]; }
    float inv = 1.0f / s;
    int i1 = 0; float b1 = lg[0];
#pragma unroll
    for (int i = 1; i < 8; ++i) if (lg[i] > b1) { b1 = lg[i]; i1 = i; }
    int i2 = -1; float b2 = -1.0f;
#pragma unroll
    for (int i = 0; i < 8; ++i)
        if (i != i1 && lg[i] > b2) { b2 = lg[i]; i2 = i; }
    if (lane == 0) {
        topi[t * 2] = i1; topi[t * 2 + 1] = i2;
        topw[t * 2] = b1 * inv; topw[t * 2 + 1] = b2 * inv;
        posb[t * 2] = atomicAdd(&counts[i1], 1);
        posb[t * 2 + 1] = atomicAdd(&counts[i2], 1);
    }
}

__global__ void scan_kernel(const int* __restrict__ counts, int* __restrict__ offsets) {
    int acc = 0;
    for (int e = 0; e < NEXP; ++e) { offsets[e] = acc; acc += counts[e]; }
}

__global__ __launch_bounds__(256)
void fill_slots(const int* __restrict__ topi, const float* __restrict__ topw,
                const int* __restrict__ posb, const int* __restrict__ offsets,
                int* __restrict__ slot_token, float* __restrict__ slot_w,
                int* __restrict__ token_slot) {
    int t = blockIdx.x * 256 + threadIdx.x;
    if (t >= NTOK) return;
#pragma unroll
    for (int k = 0; k < TOPK; ++k) {
        int e = topi[t * 2 + k];
        int sl = offsets[e] + posb[t * 2 + k];
        slot_token[sl] = t;
        slot_w[sl] = topw[t * 2 + k];
        token_slot[t * 2 + k] = sl;
    }
}

// ---------------------------------------------------------------------------
// MoE gate+up grouped GEMM. A fp32 gathered + split hi/lo; Wg/Wu bf16
// [e][IEXP][HID]. H bf16 out. Grid (12, 32, 8).
// ---------------------------------------------------------------------------
__global__ __launch_bounds__(256)
void moe_gate_up(const float* __restrict__ X, const u16* __restrict__ Wg,
                 const u16* __restrict__ Wu,
                 const int* __restrict__ slot_token,
                 const int* __restrict__ counts,
                 const int* __restrict__ offsets, u16* __restrict__ H) {
    const int e = blockIdx.z;
    const int Ce = counts[e];
    const int m0 = blockIdx.y << 7;
    if (Ce == 0 || m0 >= Ce) return;
    const int n0 = blockIdx.x << 7;
    const int base = offsets[e];
    __shared__ __align__(16) u16 Ah[4096];
    __shared__ __align__(16) u16 Al[4096];
    __shared__ __align__(16) u16 Gs[4096];
    __shared__ __align__(16) u16 Us[4096];
    const int tid = threadIdx.x, l = tid & 63, w = tid >> 6;
    const int wm = w & 1, wn = w >> 1;
    const int sr = l >> 2, sc8 = (l & 3) << 3;
    int r0 = m0 + w * 32 + sr;
    int r1 = r0 + 16;
    int t0 = slot_token[base + min(r0, Ce - 1)];
    int t1 = slot_token[base + min(r1, Ce - 1)];
    const float* gA0 = X + (size_t)t0 * HID + sc8;
    const float* gA1 = X + (size_t)t1 * HID + sc8;
    const u16* Wge = Wg + (size_t)e * IEXP * HID;
    const u16* Wue = Wu + (size_t)e * IEXP * HID;
    const u16* gG0 = Wge + (size_t)(n0 + w * 32 + sr) * HID + sc8;
    const u16* gG1 = gG0 + 16 * HID;
    const u16* gU0 = Wue + (size_t)(n0 + w * 32 + sr) * HID + sc8;
    const u16* gU1 = gU0 + 16 * HID;
    const int aoff0 = (w * 32 + sr) * 32 + sc8, aoff1 = aoff0 + 512;
    u16* lG0 = Gs + w * 1024; u16* lG1 = lG0 + 512;
    u16* lU0 = Us + w * 1024; u16* lU1 = lU0 + 512;
    const int fr = l & 15, fc = (l >> 4) << 3;
    f32x4 accg[4][4], accu[4][4];
#pragma unroll
    for (int i = 0; i < 4; ++i)
#pragma unroll
        for (int j = 0; j < 4; ++j) {
            accg[i][j] = (f32x4){0.f, 0.f, 0.f, 0.f};
            accu[i][j] = (f32x4){0.f, 0.f, 0.f, 0.f};
        }
    for (int k0 = 0; k0 < HID; k0 += 32) {
        float4 a00 = *(const float4*)(gA0 + k0);
        float4 a01 = *(const float4*)(gA0 + k0 + 4);
        float4 a10 = *(const float4*)(gA1 + k0);
        float4 a11 = *(const float4*)(gA1 + k0 + 4);
        gload16(gG0 + k0, lG0);
        gload16(gG1 + k0, lG1);
        gload16(gU0 + k0, lU0);
        gload16(gU1 + k0, lU1);
        u16x8 h0, lo0, h1, lo1;
        cvt8(a00, a01, h0, lo0);
        cvt8(a10, a11, h1, lo1);
        *(u16x8*)(Ah + aoff0) = h0; *(u16x8*)(Al + aoff0) = lo0;
        *(u16x8*)(Ah + aoff1) = h1; *(u16x8*)(Al + aoff1) = lo1;
        __syncthreads();
        bf16x8 ah[4], al[4], gf[4], uf[4];
#pragma unroll
        for (int i = 0; i < 4; ++i) {
            ah[i] = *(const bf16x8*)(Ah + (wm * 64 + i * 16 + fr) * 32 + fc);
            al[i] = *(const bf16x8*)(Al + (wm * 64 + i * 16 + fr) * 32 + fc);
            gf[i] = *(const bf16x8*)(Gs + (wn * 64 + i * 16 + fr) * 32 + fc);
            uf[i] = *(const bf16x8*)(Us + (wn * 64 + i * 16 + fr) * 32 + fc);
        }
#pragma unroll
        for (int mf = 0; mf < 4; ++mf)
#pragma unroll
            for (int nf = 0; nf < 4; ++nf) {
                accg[mf][nf] = __builtin_amdgcn_mfma_f32_16x16x32_bf16(
                    ah[mf], gf[nf], accg[mf][nf], 0, 0, 0);
                accg[mf][nf] = __builtin_amdgcn_mfma_f32_16x16x32_bf16(
                    al[mf], gf[nf], accg[mf][nf], 0, 0, 0);
                accu[mf][nf] = __builtin_amdgcn_mfma_f32_16x16x32_bf16(
                    ah[mf], uf[nf], accu[mf][nf], 0, 0, 0);
                accu[mf][nf] = __builtin_amdgcn_mfma_f32_16x16x32_bf16(
                    al[mf], uf[nf], accu[mf][nf], 0, 0, 0);
            }
        __syncthreads();
    }
    const int er = (l >> 4) << 2, ec = l & 15;
#pragma unroll
    for (int mf = 0; mf < 4; ++mf)
#pragma unroll
        for (int i = 0; i < 4; ++i) {
            int row = m0 + wm * 64 + mf * 16 + er + i;
            if (row >= Ce) continue;
            size_t sl = (size_t)(base + row);
#pragma unroll
            for (int nf = 0; nf < 4; ++nf) {
                int col = n0 + wn * 64 + nf * 16 + ec;
                float g = accg[mf][nf][i];
                float u = accu[mf][nf][i];
                float h = g / (1.0f + __expf(-g)) * u;
                H[sl * IEXP + col] = f2bf(h);
            }
        }
}

// ---------------------------------------------------------------------------
// MoE down grouped GEMM bf16: D[slot][HID] fp32 = slot_w * (H @ Wd^T)
// Wd pre-transposed to [e][HID][IEXP]. Grid (6, 32, 8).
// ---------------------------------------------------------------------------
__global__ __launch_bounds__(256)
void moe_down_bf16(const u16* __restrict__ Hb, const u16* __restrict__ Wd,
                   const float* __restrict__ slot_w,
                   const int* __restrict__ counts,
                   const int* __restrict__ offsets, float* __restrict__ D) {
    const int e = blockIdx.z;
    const int Ce = counts[e];
    const int m0 = blockIdx.y << 7;
    if (Ce == 0 || m0 >= Ce) return;
    const int n0 = blockIdx.x << 7;
    const int base = offsets[e];
    __shared__ __align__(16) u16 As[4096];
    __shared__ __align__(16) u16 Bs[4096];
    const int tid = threadIdx.x, l = tid & 63, w = tid >> 6;
    const int wm = w & 1, wn = w >> 1;
    const int sr = l >> 2, sc = (l & 3) << 3;
    const u16* Ae = Hb + (size_t)base * IEXP;
    int r0 = min(m0 + w * 32 + sr, Ce - 1);
    int r1 = min(m0 + w * 32 + 16 + sr, Ce - 1);
    const u16* gA0 = Ae + (size_t)r0 * IEXP + sc;
    const u16* gA1 = Ae + (size_t)r1 * IEXP + sc;
    const u16* Wde = Wd + (size_t)e * HID * IEXP;
    const u16* gB0 = Wde + (size_t)(n0 + w * 32 + sr) * IEXP + sc;
    const u16* gB1 = gB0 + 16 * IEXP;
    u16* lA0 = As + w * 1024; u16* lA1 = lA0 + 512;
    u16* lB0 = Bs + w * 1024; u16* lB1 = lB0 + 512;
    const int fr = l & 15, fc = (l >> 4) << 3;
    f32x4 acc[4][4];
#pragma unroll
    for (int i = 0; i < 4; ++i)
#pragma unroll
        for (int j = 0; j < 4; ++j) acc[i][j] = (f32x4){0.f, 0.f, 0.f, 0.f};
    for (int k0 = 0; k0 < IEXP; k0 += 32) {
        gload16(gA0 + k0, lA0);
        gload16(gA1 + k0, lA1);
        gload16(gB0 + k0, lB0);
        gload16(gB1 + k0, lB1);
        __syncthreads();
        bf16x8 af[4], bfv[4];
#pragma unroll
        for (int i = 0; i < 4; ++i) {
            af[i]  = *(const bf16x8*)(As + (wm * 64 + i * 16 + fr) * 32 + fc);
            bfv[i] = *(const bf16x8*)(Bs + (wn * 64 + i * 16 + fr) * 32 + fc);
        }
#pragma unroll
        for (int mf = 0; mf < 4; ++mf)
#pragma unroll
            for (int nf = 0; nf < 4; ++nf)
                acc[mf][nf] = __builtin_amdgcn_mfma_f32_16x16x32_bf16(
                    af[mf], bfv[nf], acc[mf][nf], 0, 0, 0);
        __syncthreads();
    }
    const int er = (l >> 4) << 2, ec = l & 15;
#pragma unroll
    for (int mf = 0; mf < 4; ++mf)
#pragma unroll
        for (int i = 0; i < 4; ++i) {
            int row = m0 + wm * 64 + mf * 16 + er + i;
            if (row >= Ce) continue;
            size_t sl = (size_t)(base + row);
            float sw = slot_w[sl];
#pragma unroll
            for (int nf = 0; nf < 4; ++nf) {
                int col = n0 + wn * 64 + nf * 16 + ec;
                D[sl * HID + col] = acc[mf][nf][i] * sw;
            }
        }
}

__global__ __launch_bounds__(256)
void moe_add(float* __restrict__ out, const float* __restrict__ D,
             const int* __restrict__ token_slot) {
    const int t = blockIdx.y;
    const int h = blockIdx.x * 256 + threadIdx.x;
    int s0 = token_slot[t * 2], s1 = token_slot[t * 2 + 1];
    out[(size_t)t * HID + h] += D[(size_t)s0 * HID + h] + D[(size_t)s1 * HID + h];
}

// ---------------------------------------------------------------------------
extern "C" void kernel_launch(void* const* d_in, const int* in_sizes, int n_in,
                              void* d_out, int out_size, void* d_ws, size_t ws_size,
                              hipStream_t stream) {
    const float* hidden = (const float*)d_in[0];
    const float* amask  = (const float*)d_in[1];
    const float* gmask  = (const float*)d_in[2];
    const int*   posids = (const int*)d_in[3];
    const float* ln1 = (const float*)d_in[4];
    const float* ln2 = (const float*)d_in[5];
    const float* ln3 = (const float*)d_in[6];
    const float* sqw = (const float*)d_in[7];  const float* sqb = (const float*)d_in[8];
    const float* skw = (const float*)d_in[9];  const float* skb = (const float*)d_in[10];
    const float* svw = (const float*)d_in[11]; const float* svb = (const float*)d_in[12];
    const float* sow = (const float*)d_in[13];
    const float* gqw = (const float*)d_in[14]; const float* gqb = (const float*)d_in[15];
    const float* gkw = (const float*)d_in[16]; const float* gkb = (const float*)d_in[17];
    const float* gvw = (const float*)d_in[18]; const float* gvb = (const float*)d_in[19];
    const float* gow = (const float*)d_in[20];
    const float* gatew = (const float*)d_in[21];
    const float* wg = (const float*)d_in[22];
    const float* wu = (const float*)d_in[23];
    const float* wd = (const float*)d_in[24];
    float* out = (float*)d_out;
    (void)amask;

    // ---- workspace carve (byte offsets), ~115.5 MB ----
    char* base = (char*)d_ws;
    float* xb     = (float*)(base + 0);
    float* qb     = (float*)(base + 12582912);
    float* kbuf   = (float*)(base + 25165824);
    float* vbuf   = (float*)(base + 29360128);
    float* ab     = (float*)(base + 33554432);
    u16* wqkv_sh  = (u16*)(base + 46137344);
    u16* wqkv_sl  = (u16*)(base + 48103424);
    u16* wo_sh    = (u16*)(base + 50069504);
    u16* wo_sl    = (u16*)(base + 51249152);
    u16* wqkv_gh  = (u16*)(base + 52428800);
    u16* wqkv_gl  = (u16*)(base + 54394880);
    u16* wo_gh    = (u16*)(base + 56360960);
    u16* wo_gl    = (u16*)(base + 57540608);
    u16* wgt      = (u16*)(base + 58720256);
    u16* wut      = (u16*)(base + 77594624);
    u16* wdt      = (u16*)(base + 96468992);
    float* slotw  = (float*)(base + 115343360);
    float* topw   = (float*)(base + 115376128);
    int* counts   = (int*)(base + 115408896);
    int* offsets  = (int*)(base + 115409024);
    int* topi     = (int*)(base + 115409408);
    int* posb     = (int*)(base + 115442176);
    int* slot_token = (int*)(base + 115474944);
    int* token_slot = (int*)(base + 115507712);
    // MoE-phase overlays (attention activations + attn weights dead by then):
    u16*   Hbuf  = (u16*)  (base + 12582912);   // 25,165,824 B
    float* Dbuf  = (float*)(base + 37748736);   // 25,165,824 B (clobbers attn W + wgt head; both done)

    // ---- weight prep ----
    cvt_split<<<576, 256, 0, stream>>>(sqw, wqkv_sh, wqkv_sl, 589824);
    cvt_split<<<192, 256, 0, stream>>>(skw, wqkv_sh + 589824, wqkv_sl + 589824, 196608);
    cvt_split<<<192, 256, 0, stream>>>(svw, wqkv_sh + 786432, wqkv_sl + 786432, 196608);
    cvt_split<<<576, 256, 0, stream>>>(sow, wo_sh, wo_sl, 589824);
    cvt_split<<<576, 256, 0, stream>>>(gqw, wqkv_gh, wqkv_gl, 589824);
    cvt_split<<<192, 256, 0, stream>>>(gkw, wqkv_gh + 589824, wqkv_gl + 589824, 196608);
    cvt_split<<<192, 256, 0, stream>>>(gvw, wqkv_gh + 786432, wqkv_gl + 786432, 196608);
    cvt_split<<<576, 256, 0, stream>>>(gow, wo_gh, wo_gl, 589824);
    transpose_cvt<<<dim3(48, 24, 8), dim3(32, 8), 0, stream>>>(wg, wgt, HID, IEXP);
    transpose_cvt<<<dim3(48, 24, 8), dim3(32, 8), 0, stream>>>(wu, wut, HID, IEXP);
    transpose_cvt<<<dim3(24, 48, 8), dim3(32, 8), 0, stream>>>(wd, wdt, IEXP, HID);

    // ---- self attention ----
    rmsnorm_kernel<<<NTOK, 256, 0, stream>>>(hidden, ln1, xb);
    qkv_split<<<dim3(10, 32), 256, 0, stream>>>(xb, wqkv_sh, wqkv_sl,
                                                sqb, skb, svb, qb, kbuf, vbuf);
    rope_kernel<<<NTOK, 256, 0, stream>>>(qb, kbuf, posids);
    attn_self_mfma<<<dim3(SEQ / 32, NHEAD, BATCH), 256, 0, stream>>>(qb, kbuf, vbuf, ab);
    oproj_split<<<dim3(6, 32), 256, 0, stream>>>(ab, wo_sh, wo_sl, hidden, out,
                                                 NTOK, HID, HID);

    // ---- group attention ----
    rmsnorm_kernel<<<NTOK, 256, 0, stream>>>(out, ln2, xb);
    qkv_split<<<dim3(10, 32), 256, 0, stream>>>(xb, wqkv_gh, wqkv_gl,
                                                gqb, gkb, gvb, qb, kbuf, vbuf);
    attn_group<<<SEQ * NHEAD, 64, 0, stream>>>(qb, kbuf, vbuf, gmask, ab);
    oproj_split<<<dim3(6, 32), 256, 0, stream>>>(ab, wo_gh, wo_gl, out, out,
                                                 NTOK, HID, HID);

    // ---- MoE (bf16 MFMA: post-router, flip-free) ----
    rmsnorm_kernel<<<NTOK, 256, 0, stream>>>(out, ln3, xb);
    hipMemsetAsync(counts, 0, 8 * sizeof(int), stream);
    router_kernel<<<NTOK, 64, 0, stream>>>(xb, gatew, counts, topi, topw, posb);
    scan_kernel<<<1, 1, 0, stream>>>(counts, offsets);
    fill_slots<<<16, 256, 0, stream>>>(topi, topw, posb, offsets,
                                       slot_token, slotw, token_slot);
    moe_gate_up<<<dim3(12, 32, 8), 256, 0, stream>>>(
        xb, wgt, wut, slot_token, counts, offsets, Hbuf);
    moe_down_bf16<<<dim3(6, 32, 8), 256, 0, stream>>>(
        Hbuf, wdt, slotw, counts, offsets, Dbuf);
    moe_add<<<dim3(3, NTOK), 256, 0, stream>>>(out, Dbuf, token_slot);
}